// Round 4
// baseline (745.831 us; speedup 1.0000x reference)
//
#include <hip/hip_runtime.h>

#define NN 4096
#define NE 131072
#define DIN 256
#define DHID 512
#define DOUT 64
#define NBINS 65536
#define HALF_E 65536

// ---------------- Threefry-2x32 (JAX-compatible) ----------------
struct K2 { unsigned a, b; };
__host__ __device__ constexpr unsigned rotl32(unsigned x, unsigned d){ return (x<<d)|(x>>(32u-d)); }
__host__ __device__ constexpr K2 tf2x32(unsigned k0, unsigned k1, unsigned x0, unsigned x1){
  unsigned k2 = k0 ^ k1 ^ 0x1BD11BDAu;
  x0 += k0; x1 += k1;
  x0+=x1; x1=rotl32(x1,13); x1^=x0;
  x0+=x1; x1=rotl32(x1,15); x1^=x0;
  x0+=x1; x1=rotl32(x1,26); x1^=x0;
  x0+=x1; x1=rotl32(x1, 6); x1^=x0;
  x0+=k1; x1+=k2+1u;
  x0+=x1; x1=rotl32(x1,17); x1^=x0;
  x0+=x1; x1=rotl32(x1,29); x1^=x0;
  x0+=x1; x1=rotl32(x1,16); x1^=x0;
  x0+=x1; x1=rotl32(x1,24); x1^=x0;
  x0+=k2; x1+=k0+2u;
  x0+=x1; x1=rotl32(x1,13); x1^=x0;
  x0+=x1; x1=rotl32(x1,15); x1^=x0;
  x0+=x1; x1=rotl32(x1,26); x1^=x0;
  x0+=x1; x1=rotl32(x1, 6); x1^=x0;
  x0+=k0; x1+=k1+3u;
  x0+=x1; x1=rotl32(x1,17); x1^=x0;
  x0+=x1; x1=rotl32(x1,29); x1^=x0;
  x0+=x1; x1=rotl32(x1,16); x1^=x0;
  x0+=x1; x1=rotl32(x1,24); x1^=x0;
  x0+=k1; x1+=k2+4u;
  x0+=x1; x1=rotl32(x1,13); x1^=x0;
  x0+=x1; x1=rotl32(x1,15); x1^=x0;
  x0+=x1; x1=rotl32(x1,26); x1^=x0;
  x0+=x1; x1=rotl32(x1, 6); x1^=x0;
  x0+=k2; x1+=k0+5u;
  return K2{x0,x1};
}
// Cipher KAT (original-mode split(PRNGKey(0)) values — validates the cipher itself)
static_assert(tf2x32(0u,0u,0u,2u).a==4146024105u, "threefry mismatch o0");
static_assert(tf2x32(0u,0u,0u,2u).b==2718843009u, "threefry mismatch o1");
static_assert(tf2x32(0u,0u,1u,3u).a==967050713u,  "threefry mismatch o0b");
static_assert(tf2x32(0u,0u,1u,3u).b==1272950319u, "threefry mismatch o1b");

// ---- jax_threefry_partitionable=True (default since JAX 0.4.36) derivation ----
// split(key)[i]              = threefry(key, (0,i))          (full 64-bit output)
// random_bits(key,32,(n,))[i] = let (b1,b2)=threefry(key,(0,i)) in b1 ^ b2
// _shuffle(key(42)), 2 rounds: key1,sub1 = split(key0); key2,sub2 = split(key1)
constexpr K2 E0 = tf2x32(0u,42u,0u,0u);     // key1
constexpr K2 E1 = tf2x32(0u,42u,0u,1u);     // sub1
constexpr unsigned SK1A = E1.a, SK1B = E1.b;
constexpr K2 F1 = tf2x32(E0.a,E0.b,0u,1u);  // sub2
constexpr unsigned SK2A = F1.a, SK2B = F1.b;

__global__ void gen_keys(unsigned* __restrict__ keys1, unsigned* __restrict__ keys2){
  unsigned i = blockIdx.x*256u + threadIdx.x;          // 0..NE-1
  K2 r1 = tf2x32(SK1A, SK1B, 0u, i);
  keys1[i] = r1.a ^ r1.b;
  K2 r2 = tf2x32(SK2A, SK2B, 0u, i);
  keys2[i] = r2.a ^ r2.b;
}

// ---------------- generic exclusive scan (n = nb*256, nb<=256) ----------------
__global__ void scan_local(unsigned* data, unsigned* bsum){
  __shared__ unsigned s[256];
  int t = threadIdx.x; unsigned i = blockIdx.x*256u + t;
  unsigned v = data[i]; s[t] = v; __syncthreads();
  for (int off=1; off<256; off<<=1){
    unsigned u = (t>=off) ? s[t-off] : 0u;
    __syncthreads(); s[t] += u; __syncthreads();
  }
  data[i] = s[t] - v;
  if (t==255) bsum[blockIdx.x] = s[255];
}
__global__ void scan_single(unsigned* bsum, int nb){
  __shared__ unsigned s[256];
  int t = threadIdx.x; unsigned v = (t<nb) ? bsum[t] : 0u; s[t]=v; __syncthreads();
  for (int off=1; off<256; off<<=1){
    unsigned u = (t>=off) ? s[t-off] : 0u;
    __syncthreads(); s[t] += u; __syncthreads();
  }
  if (t<nb) bsum[t] = s[t] - v;
}
__global__ void scan_addoff(unsigned* data, const unsigned* bsum){
  data[blockIdx.x*256u + threadIdx.x] += bsum[blockIdx.x];
}

// ---------------- rank passes (stable sort emulation) ----------------
__global__ void hist1_k(const unsigned* __restrict__ keys1, unsigned* __restrict__ hist){
  int e = blockIdx.x*256 + threadIdx.x;
  atomicAdd(&hist[keys1[e]>>16], 1u);
}
__global__ void scat1_k(const unsigned* __restrict__ keys1, unsigned* __restrict__ cursor,
                        unsigned* __restrict__ slow, unsigned* __restrict__ stb){
  int e = blockIdx.x*256 + threadIdx.x;
  unsigned k = keys1[e];
  unsigned p = atomicAdd(&cursor[k>>16], 1u);
  slow[p] = k & 0xFFFFu; stb[p] = (unsigned)e;
}
__global__ void rank1_k(const unsigned* __restrict__ keys1, const unsigned* __restrict__ prefix,
                        const unsigned* __restrict__ hist, const unsigned* __restrict__ slow,
                        const unsigned* __restrict__ stb, unsigned* __restrict__ rank1){
  int e = blockIdx.x*256 + threadIdx.x;
  unsigned k = keys1[e], h = k>>16, lo = k & 0xFFFFu, tb = (unsigned)e;
  unsigned base = prefix[h], n = hist[h], r = 0;
  for (unsigned j=0;j<n;j++){
    unsigned l2 = slow[base+j], t2 = stb[base+j];
    if (l2 < lo || (l2==lo && t2 < tb)) r++;
  }
  rank1[e] = base + r;
}
__global__ void hist2_k(const unsigned* __restrict__ keys2, const unsigned* __restrict__ rank1,
                        unsigned* __restrict__ hist){
  int e = blockIdx.x*256 + threadIdx.x;
  atomicAdd(&hist[keys2[rank1[e]]>>16], 1u);
}
__global__ void scat2_k(const unsigned* __restrict__ keys2, const unsigned* __restrict__ rank1,
                        unsigned* __restrict__ cursor, unsigned* __restrict__ slow, unsigned* __restrict__ stb){
  int e = blockIdx.x*256 + threadIdx.x;
  unsigned rk = rank1[e], k = keys2[rk];
  unsigned p = atomicAdd(&cursor[k>>16], 1u);
  slow[p] = k & 0xFFFFu; stb[p] = rk;
}
__global__ void rank2_k(const unsigned* __restrict__ keys2, const unsigned* __restrict__ rank1,
                        const unsigned* __restrict__ prefix, const unsigned* __restrict__ hist,
                        const unsigned* __restrict__ slow, const unsigned* __restrict__ stb,
                        unsigned* __restrict__ keep){
  int e = blockIdx.x*256 + threadIdx.x;
  unsigned rk = rank1[e], k = keys2[rk], h = k>>16, lo = k & 0xFFFFu;
  unsigned base = prefix[h], n = hist[h], r = 0;
  for (unsigned j=0;j<n;j++){
    unsigned l2 = slow[base+j], t2 = stb[base+j];
    if (l2 < lo || (l2==lo && t2 < rk)) r++;
  }
  keep[e] = (base + r >= HALF_E) ? 1u : 0u;   // perm[:E/2] are dropped
}

// ---------------- graph CSR ----------------
__global__ void degrees_k(const int* __restrict__ ei, unsigned* __restrict__ indeg, unsigned* __restrict__ outdeg){
  int e = blockIdx.x*256 + threadIdx.x;
  atomicAdd(&outdeg[ei[e]], 1u);
  atomicAdd(&indeg[ei[NE+e]], 1u);
}
__global__ void scatter_edges_k(const int* __restrict__ ei, const unsigned* __restrict__ keep,
                                unsigned* __restrict__ curin, unsigned* __restrict__ curout,
                                unsigned* __restrict__ in_list, unsigned* __restrict__ out_list){
  int e = blockIdx.x*256 + threadIdx.x;
  unsigned s = (unsigned)ei[e], d = (unsigned)ei[NE+e];
  unsigned p = atomicAdd(&curin[d], 1u);  in_list[p] = s;
  unsigned q = atomicAdd(&curout[s], 1u); out_list[q] = d | (keep[e]<<31);
}
__global__ void selfbits_k(unsigned* __restrict__ bits){
  int i = blockIdx.x*256 + threadIdx.x;   // 4096
  bits[i*128 + (i>>5)] = (1u << (i&31));
}
__global__ void edgebits_k(const int* __restrict__ ei, unsigned* __restrict__ bits){
  int e = blockIdx.x*256 + threadIdx.x;
  unsigned s = (unsigned)ei[e], d = (unsigned)ei[NE+e];
  atomicOr(&bits[d*128 + (s>>5)], 1u << (s&31));
}

// ---------------- ego: reach row (2-hop) -> mean of x rows ----------------
__global__ void ego_k(const unsigned* __restrict__ bits, const unsigned* __restrict__ in_off,
                      const unsigned* __restrict__ in_list, const unsigned* __restrict__ indeg,
                      const float* __restrict__ x, float* __restrict__ ego){
  __shared__ unsigned row[128];
  __shared__ float cnt_s;
  int i = blockIdx.x, t = threadIdx.x;
  unsigned off = in_off[i], deg = indeg[i];
  if (t < 128){
    unsigned acc = bits[i*128 + t];         // onehop of self covers {i} U in(i)
    for (unsigned j=0;j<deg;j++){
      unsigned k = in_list[off+j];
      acc |= bits[k*128 + t];
    }
    row[t] = acc;
  }
  __syncthreads();
  if (t==0){ int c=0; for (int w=0;w<128;w++) c += __popc(row[w]); cnt_s = (float)c; }
  __syncthreads();
  float inv = 1.0f / cnt_s;
  float acc = 0.f;
  for (int w=0; w<128; w++){
    unsigned m = row[w];
    int base = w<<5;
    while (m){
      int j = base + __ffs(m) - 1; m &= m-1u;
      acc += x[j*DIN + t];
    }
  }
  ego[i*DIN + t] = acc * inv;
}

// ---------------- cut feature ----------------
__global__ void cut_k(const float* __restrict__ x, const unsigned* __restrict__ out_off,
                      const unsigned* __restrict__ outdeg, const unsigned* __restrict__ out_list,
                      float* __restrict__ cut){
  int s = blockIdx.x, t = threadIdx.x;
  unsigned off = out_off[s], deg = outdeg[s];
  float acc = 0.f; int cnt = 0;
  for (unsigned j=0;j<deg;j++){
    unsigned p = out_list[off+j];
    if (p >> 31){ cnt++; acc += x[(p & 0xFFFFu)*DIN + t]; }
  }
  cut[s*DIN + t] = cnt ? acc / (float)cnt : x[s*DIN + t];
}

// ---------------- f32 tiled GEMM: C[MxN] = A[MxK]@B[KxN] + bias ----------------
__global__ void gemm_f32(const float* __restrict__ A, int lda,
                         const float* __restrict__ B, int ldb,
                         const float* __restrict__ bias,
                         float* __restrict__ C, int ldc, int K){
  __shared__ float As[16][65];
  __shared__ float Bs[16][64];
  int t = threadIdx.x;
  int tx = t & 15, ty = t >> 4;
  int m0 = blockIdx.y*64, n0 = blockIdx.x*64;
  int arow = t >> 2, acol = (t & 3)*4;
  int brow = t >> 4, bcol = (t & 15)*4;
  float acc[4][4] = {};
  for (int k0=0; k0<K; k0+=16){
    float4 av = *(const float4*)&A[(size_t)(m0+arow)*lda + k0 + acol];
    float4 bv = *(const float4*)&B[(size_t)(k0+brow)*ldb + n0 + bcol];
    As[acol+0][arow]=av.x; As[acol+1][arow]=av.y; As[acol+2][arow]=av.z; As[acol+3][arow]=av.w;
    *(float4*)&Bs[brow][bcol] = bv;
    __syncthreads();
    #pragma unroll
    for (int kk=0; kk<16; kk++){
      float a0=As[kk][ty*4], a1=As[kk][ty*4+1], a2=As[kk][ty*4+2], a3=As[kk][ty*4+3];
      float b0=Bs[kk][tx*4], b1=Bs[kk][tx*4+1], b2=Bs[kk][tx*4+2], b3=Bs[kk][tx*4+3];
      acc[0][0]+=a0*b0; acc[0][1]+=a0*b1; acc[0][2]+=a0*b2; acc[0][3]+=a0*b3;
      acc[1][0]+=a1*b0; acc[1][1]+=a1*b1; acc[1][2]+=a1*b2; acc[1][3]+=a1*b3;
      acc[2][0]+=a2*b0; acc[2][1]+=a2*b1; acc[2][2]+=a2*b2; acc[2][3]+=a2*b3;
      acc[3][0]+=a3*b0; acc[3][1]+=a3*b1; acc[3][2]+=a3*b2; acc[3][3]+=a3*b3;
    }
    __syncthreads();
  }
  for (int i2=0;i2<4;i2++){
    int r = m0 + ty*4 + i2;
    for (int j2=0;j2<4;j2++){
      int c = n0 + tx*4 + j2;
      C[(size_t)r*ldc + c] = acc[i2][j2] + bias[c];
    }
  }
}

// ---------------- fused: agg(in-edges) -> relu -> @fcW_block -> out (+=) ----------------
template<int ADDBIAS>
__global__ void aggfc_k(const float* __restrict__ h, const unsigned* __restrict__ in_off,
                        const unsigned* __restrict__ indeg, const unsigned* __restrict__ in_list,
                        const float* __restrict__ fcW, const float* __restrict__ fcb,
                        float* __restrict__ out){
  __shared__ float row[DHID];
  int i = blockIdx.x, t = threadIdx.x;
  unsigned off = in_off[i], deg = indeg[i];
  float a0=0.f, a1=0.f;
  for (unsigned j=0;j<deg;j++){
    unsigned s = in_list[off+j];
    a0 += h[(size_t)s*DHID + t];
    a1 += h[(size_t)s*DHID + t + 256];
  }
  row[t]     = fmaxf(a0, 0.f);
  row[t+256] = fmaxf(a1, 0.f);
  __syncthreads();
  if (t < DOUT){
    float acc = ADDBIAS ? fcb[t] : 0.f;
    for (int k=0;k<DHID;k++) acc += row[k] * fcW[k*DOUT + t];
    if (ADDBIAS) out[i*DOUT + t] = acc;
    else         out[i*DOUT + t] += acc;
  }
}

// ---------------- glob branch: henc row (no relu) @ fcW_block -> out += ----------------
// NOTE: MUST be launched with 256 threads (fills row[0..255] and row[256..511]).
__global__ void globfc_k(const float* __restrict__ h, const float* __restrict__ fcW,
                         float* __restrict__ out){
  __shared__ float row[DHID];
  int i = blockIdx.x, t = threadIdx.x;
  row[t]     = h[(size_t)i*DHID + t];
  row[t+256] = h[(size_t)i*DHID + t + 256];
  __syncthreads();
  if (t < DOUT){
    float acc = 0.f;
    for (int k=0;k<DHID;k++) acc += row[k] * fcW[k*DOUT + t];
    out[i*DOUT + t] += acc;
  }
}

// ---------------- log_softmax over rows of 64 ----------------
__global__ void logsoftmax_k(float* __restrict__ out){
  int i = blockIdx.x, l = threadIdx.x;
  float v = out[i*DOUT + l];
  float m = v;
  for (int o=32;o>0;o>>=1) m = fmaxf(m, __shfl_xor(m, o, 64));
  float e = __expf(v - m), s = e;
  for (int o=32;o>0;o>>=1) s += __shfl_xor(s, o, 64);
  out[i*DOUT + l] = (v - m) - logf(s);
}

// ---------------- host launch ----------------
static inline size_t alignup(size_t x){ return (x + 255) & ~(size_t)255; }

extern "C" void kernel_launch(void* const* d_in, const int* in_sizes, int n_in,
                              void* d_out, int out_size, void* d_ws, size_t ws_size,
                              hipStream_t stream) {
  const float* x      = (const float*)d_in[0];
  const int*   ei     = (const int*)  d_in[1];
  const float* ego_W  = (const float*)d_in[2];
  const float* ego_b  = (const float*)d_in[3];
  const float* cut_W  = (const float*)d_in[4];
  const float* cut_b  = (const float*)d_in[5];
  const float* glob_W = (const float*)d_in[6];
  const float* glob_b = (const float*)d_in[7];
  const float* fc_W   = (const float*)d_in[8];
  const float* fc_b   = (const float*)d_in[9];
  float* out = (float*)d_out;

  // ---- workspace layout (~19.6 MB peak) ----
  char* base = (char*)d_ws;
  char* p = base;
  #define ALLOC(ty, name, cnt) ty* name = (ty*)p; p += alignup(sizeof(ty)*(size_t)(cnt));
  ALLOC(float,    henc,    (size_t)NN*DHID);   // 8 MB; also hosts sort temps (dead before 1st GEMM)
  ALLOC(unsigned, keep,    NE);
  ALLOC(unsigned, indeg,   NN);
  ALLOC(unsigned, outdeg,  NN);
  ALLOC(unsigned, in_off,  NN);
  ALLOC(unsigned, out_off, NN);
  ALLOC(unsigned, curin,   NN);
  ALLOC(unsigned, curout,  NN);
  ALLOC(unsigned, in_list, NE);
  ALLOC(unsigned, out_list,NE);
  ALLOC(unsigned, bits,    NN*128);
  ALLOC(float,    ego,     (size_t)NN*DIN);
  ALLOC(float,    cut,     (size_t)NN*DIN);
  #undef ALLOC
  size_t need = (size_t)(p - base);
  if (ws_size < need){
    hipMemsetAsync(d_out, 0x7F, (size_t)out_size*sizeof(float), stream);
    return;
  }
  // sort temps overlaid inside henc (3.3 MB < 8 MB); dead before henc's first write
  char* q = (char*)henc;
  #define OALLOC(ty, name, cnt) ty* name = (ty*)q; q += alignup(sizeof(ty)*(size_t)(cnt));
  OALLOC(unsigned, keys1,  NE);
  OALLOC(unsigned, keys2,  NE);
  OALLOC(unsigned, rank1,  NE);
  OALLOC(unsigned, slow,   NE);
  OALLOC(unsigned, stb,    NE);
  OALLOC(unsigned, hist,   NBINS);
  OALLOC(unsigned, prefix, NBINS);
  OALLOC(unsigned, cursor, NBINS);
  OALLOC(unsigned, bsum,   256);
  #undef OALLOC

  const int EB = NE/256;   // 512 blocks for per-edge kernels

  auto scan = [&](unsigned* data, int n){
    int nb = n/256;
    hipLaunchKernelGGL(scan_local, dim3(nb), dim3(256), 0, stream, data, bsum);
    hipLaunchKernelGGL(scan_single, dim3(1), dim3(256), 0, stream, bsum, nb);
    hipLaunchKernelGGL(scan_addoff, dim3(nb), dim3(256), 0, stream, data, bsum);
  };

  // ---- keep mask (2-round stable-sort ranks, partitionable threefry, xor words) ----
  hipLaunchKernelGGL(gen_keys, dim3(EB), dim3(256), 0, stream, keys1, keys2);
  hipMemsetAsync(hist, 0, NBINS*4, stream);
  hipLaunchKernelGGL(hist1_k, dim3(EB), dim3(256), 0, stream, keys1, hist);
  hipMemcpyAsync(prefix, hist, NBINS*4, hipMemcpyDeviceToDevice, stream);
  scan(prefix, NBINS);
  hipMemcpyAsync(cursor, prefix, NBINS*4, hipMemcpyDeviceToDevice, stream);
  hipLaunchKernelGGL(scat1_k, dim3(EB), dim3(256), 0, stream, keys1, cursor, slow, stb);
  hipLaunchKernelGGL(rank1_k, dim3(EB), dim3(256), 0, stream, keys1, prefix, hist, slow, stb, rank1);
  hipMemsetAsync(hist, 0, NBINS*4, stream);
  hipLaunchKernelGGL(hist2_k, dim3(EB), dim3(256), 0, stream, keys2, rank1, hist);
  hipMemcpyAsync(prefix, hist, NBINS*4, hipMemcpyDeviceToDevice, stream);
  scan(prefix, NBINS);
  hipMemcpyAsync(cursor, prefix, NBINS*4, hipMemcpyDeviceToDevice, stream);
  hipLaunchKernelGGL(scat2_k, dim3(EB), dim3(256), 0, stream, keys2, rank1, cursor, slow, stb);
  hipLaunchKernelGGL(rank2_k, dim3(EB), dim3(256), 0, stream, keys2, rank1, prefix, hist, slow, stb, keep);

  // ---- CSR ----
  hipMemsetAsync(indeg,  0, NN*4, stream);
  hipMemsetAsync(outdeg, 0, NN*4, stream);
  hipLaunchKernelGGL(degrees_k, dim3(EB), dim3(256), 0, stream, ei, indeg, outdeg);
  hipMemcpyAsync(in_off,  indeg,  NN*4, hipMemcpyDeviceToDevice, stream);
  hipMemcpyAsync(out_off, outdeg, NN*4, hipMemcpyDeviceToDevice, stream);
  scan(in_off, NN);
  scan(out_off, NN);
  hipMemcpyAsync(curin,  in_off,  NN*4, hipMemcpyDeviceToDevice, stream);
  hipMemcpyAsync(curout, out_off, NN*4, hipMemcpyDeviceToDevice, stream);
  hipLaunchKernelGGL(scatter_edges_k, dim3(EB), dim3(256), 0, stream, ei, keep, curin, curout, in_list, out_list);

  // ---- one-hop bitsets ----
  hipMemsetAsync(bits, 0, (size_t)NN*128*4, stream);
  hipLaunchKernelGGL(selfbits_k, dim3(NN/256), dim3(256), 0, stream, bits);
  hipLaunchKernelGGL(edgebits_k, dim3(EB), dim3(256), 0, stream, ei, bits);

  // ---- features ----
  hipLaunchKernelGGL(ego_k, dim3(NN), dim3(256), 0, stream, bits, in_off, in_list, indeg, x, ego);
  hipLaunchKernelGGL(cut_k, dim3(NN), dim3(256), 0, stream, x, out_off, outdeg, out_list, cut);

  // ---- branch 1: ego -> henc -> agg+relu -> fc block 0 (writes out with fc bias) ----
  hipLaunchKernelGGL(gemm_f32, dim3(DHID/64, NN/64), dim3(256), 0, stream,
                     ego, DIN, ego_W, DHID, ego_b, henc, DHID, DIN);
  hipLaunchKernelGGL((aggfc_k<1>), dim3(NN), dim3(256), 0, stream,
                     henc, in_off, indeg, in_list, fc_W, fc_b, out);
  // ---- branch 2: cut -> henc -> agg+relu -> fc block 1 (out +=) ----
  hipLaunchKernelGGL(gemm_f32, dim3(DHID/64, NN/64), dim3(256), 0, stream,
                     cut, DIN, cut_W, DHID, cut_b, henc, DHID, DIN);
  hipLaunchKernelGGL((aggfc_k<0>), dim3(NN), dim3(256), 0, stream,
                     henc, in_off, indeg, in_list, fc_W + (size_t)DHID*DOUT, fc_b, out);
  // ---- branch 3: glob -> henc -> fc block 2 (out +=) ----
  hipLaunchKernelGGL(gemm_f32, dim3(DHID/64, NN/64), dim3(256), 0, stream,
                     x, DIN, glob_W, DHID, glob_b, henc, DHID, DIN);
  hipLaunchKernelGGL(globfc_k, dim3(NN), dim3(256), 0, stream,
                     henc, fc_W + (size_t)2*DHID*DOUT, out);

  hipLaunchKernelGGL(logsoftmax_k, dim3(NN), dim3(64), 0, stream, out);
}

// Round 5
// 395.852 us; speedup vs baseline: 1.8841x; 1.8841x over previous
//
#include <hip/hip_runtime.h>

#define NN 4096
#define NE 131072
#define DIN 256
#define DHID 512
#define DOUT 64
#define NBINS 65536
#define HALF_E 65536

typedef __attribute__((ext_vector_type(8))) short short8;
typedef __attribute__((ext_vector_type(4))) float f32x4;

__device__ inline unsigned short bf16rne(float f){
  unsigned u = __float_as_uint(f);
  unsigned r = u + 0x7FFFu + ((u>>16)&1u);
  return (unsigned short)(r>>16);
}

// ---------------- Threefry-2x32 (JAX-compatible) ----------------
struct K2 { unsigned a, b; };
__host__ __device__ constexpr unsigned rotl32(unsigned x, unsigned d){ return (x<<d)|(x>>(32u-d)); }
__host__ __device__ constexpr K2 tf2x32(unsigned k0, unsigned k1, unsigned x0, unsigned x1){
  unsigned k2 = k0 ^ k1 ^ 0x1BD11BDAu;
  x0 += k0; x1 += k1;
  x0+=x1; x1=rotl32(x1,13); x1^=x0;
  x0+=x1; x1=rotl32(x1,15); x1^=x0;
  x0+=x1; x1=rotl32(x1,26); x1^=x0;
  x0+=x1; x1=rotl32(x1, 6); x1^=x0;
  x0+=k1; x1+=k2+1u;
  x0+=x1; x1=rotl32(x1,17); x1^=x0;
  x0+=x1; x1=rotl32(x1,29); x1^=x0;
  x0+=x1; x1=rotl32(x1,16); x1^=x0;
  x0+=x1; x1=rotl32(x1,24); x1^=x0;
  x0+=k2; x1+=k0+2u;
  x0+=x1; x1=rotl32(x1,13); x1^=x0;
  x0+=x1; x1=rotl32(x1,15); x1^=x0;
  x0+=x1; x1=rotl32(x1,26); x1^=x0;
  x0+=x1; x1=rotl32(x1, 6); x1^=x0;
  x0+=k0; x1+=k1+3u;
  x0+=x1; x1=rotl32(x1,17); x1^=x0;
  x0+=x1; x1=rotl32(x1,29); x1^=x0;
  x0+=x1; x1=rotl32(x1,16); x1^=x0;
  x0+=x1; x1=rotl32(x1,24); x1^=x0;
  x0+=k1; x1+=k2+4u;
  x0+=x1; x1=rotl32(x1,13); x1^=x0;
  x0+=x1; x1=rotl32(x1,15); x1^=x0;
  x0+=x1; x1=rotl32(x1,26); x1^=x0;
  x0+=x1; x1=rotl32(x1, 6); x1^=x0;
  x0+=k2; x1+=k0+5u;
  return K2{x0,x1};
}
static_assert(tf2x32(0u,0u,0u,2u).a==4146024105u, "threefry mismatch o0");
static_assert(tf2x32(0u,0u,0u,2u).b==2718843009u, "threefry mismatch o1");
static_assert(tf2x32(0u,0u,1u,3u).a==967050713u,  "threefry mismatch o0b");
static_assert(tf2x32(0u,0u,1u,3u).b==1272950319u, "threefry mismatch o1b");

// jax_threefry_partitionable derivation (verified passing in round 4):
// split(key)[i] = threefry(key,(0,i)); random_bits 32[i] = a^b of threefry(key,(0,i))
constexpr K2 E0 = tf2x32(0u,42u,0u,0u);     // key1
constexpr K2 E1 = tf2x32(0u,42u,0u,1u);     // sub1
constexpr unsigned SK1A = E1.a, SK1B = E1.b;
constexpr K2 F1 = tf2x32(E0.a,E0.b,0u,1u);  // sub2
constexpr unsigned SK2A = F1.a, SK2B = F1.b;

__global__ void gen_keys(unsigned* __restrict__ keys1, unsigned* __restrict__ keys2){
  unsigned i = blockIdx.x*256u + threadIdx.x;
  K2 r1 = tf2x32(SK1A, SK1B, 0u, i);
  keys1[i] = r1.a ^ r1.b;
  K2 r2 = tf2x32(SK2A, SK2B, 0u, i);
  keys2[i] = r2.a ^ r2.b;
}

// ---------------- generic exclusive scan ----------------
__global__ void scan_local(unsigned* data, unsigned* bsum){
  __shared__ unsigned s[256];
  int t = threadIdx.x; unsigned i = blockIdx.x*256u + t;
  unsigned v = data[i]; s[t] = v; __syncthreads();
  for (int off=1; off<256; off<<=1){
    unsigned u = (t>=off) ? s[t-off] : 0u;
    __syncthreads(); s[t] += u; __syncthreads();
  }
  data[i] = s[t] - v;
  if (t==255) bsum[blockIdx.x] = s[255];
}
__global__ void scan_single(unsigned* bsum, int nb){
  __shared__ unsigned s[256];
  int t = threadIdx.x; unsigned v = (t<nb) ? bsum[t] : 0u; s[t]=v; __syncthreads();
  for (int off=1; off<256; off<<=1){
    unsigned u = (t>=off) ? s[t-off] : 0u;
    __syncthreads(); s[t] += u; __syncthreads();
  }
  if (t<nb) bsum[t] = s[t] - v;
}
__global__ void scan_addoff(unsigned* data, const unsigned* bsum){
  data[blockIdx.x*256u + threadIdx.x] += bsum[blockIdx.x];
}

// ---------------- rank passes ----------------
__global__ void hist1_k(const unsigned* __restrict__ keys1, unsigned* __restrict__ hist){
  int e = blockIdx.x*256 + threadIdx.x;
  atomicAdd(&hist[keys1[e]>>16], 1u);
}
__global__ void scat1_k(const unsigned* __restrict__ keys1, unsigned* __restrict__ cursor,
                        unsigned* __restrict__ slow, unsigned* __restrict__ stb){
  int e = blockIdx.x*256 + threadIdx.x;
  unsigned k = keys1[e];
  unsigned p = atomicAdd(&cursor[k>>16], 1u);
  slow[p] = k & 0xFFFFu; stb[p] = (unsigned)e;
}
__global__ void rank1_k(const unsigned* __restrict__ keys1, const unsigned* __restrict__ prefix,
                        const unsigned* __restrict__ hist, const unsigned* __restrict__ slow,
                        const unsigned* __restrict__ stb, unsigned* __restrict__ rank1){
  int e = blockIdx.x*256 + threadIdx.x;
  unsigned k = keys1[e], h = k>>16, lo = k & 0xFFFFu, tb = (unsigned)e;
  unsigned base = prefix[h], n = hist[h], r = 0;
  for (unsigned j=0;j<n;j++){
    unsigned l2 = slow[base+j], t2 = stb[base+j];
    if (l2 < lo || (l2==lo && t2 < tb)) r++;
  }
  rank1[e] = base + r;
}
__global__ void hist2_k(const unsigned* __restrict__ keys2, const unsigned* __restrict__ rank1,
                        unsigned* __restrict__ hist){
  int e = blockIdx.x*256 + threadIdx.x;
  atomicAdd(&hist[keys2[rank1[e]]>>16], 1u);
}
__global__ void scat2_k(const unsigned* __restrict__ keys2, const unsigned* __restrict__ rank1,
                        unsigned* __restrict__ cursor, unsigned* __restrict__ slow, unsigned* __restrict__ stb){
  int e = blockIdx.x*256 + threadIdx.x;
  unsigned rk = rank1[e], k = keys2[rk];
  unsigned p = atomicAdd(&cursor[k>>16], 1u);
  slow[p] = k & 0xFFFFu; stb[p] = rk;
}
__global__ void rank2_k(const unsigned* __restrict__ keys2, const unsigned* __restrict__ rank1,
                        const unsigned* __restrict__ prefix, const unsigned* __restrict__ hist,
                        const unsigned* __restrict__ slow, const unsigned* __restrict__ stb,
                        unsigned* __restrict__ keep){
  int e = blockIdx.x*256 + threadIdx.x;
  unsigned rk = rank1[e], k = keys2[rk], h = k>>16, lo = k & 0xFFFFu;
  unsigned base = prefix[h], n = hist[h], r = 0;
  for (unsigned j=0;j<n;j++){
    unsigned l2 = slow[base+j], t2 = stb[base+j];
    if (l2 < lo || (l2==lo && t2 < rk)) r++;
  }
  keep[e] = (base + r >= HALF_E) ? 1u : 0u;
}

// ---------------- graph CSR ----------------
__global__ void degrees_k(const int* __restrict__ ei, unsigned* __restrict__ indeg, unsigned* __restrict__ outdeg){
  int e = blockIdx.x*256 + threadIdx.x;
  atomicAdd(&outdeg[ei[e]], 1u);
  atomicAdd(&indeg[ei[NE+e]], 1u);
}
__global__ void scatter_edges_k(const int* __restrict__ ei, const unsigned* __restrict__ keep,
                                unsigned* __restrict__ curin, unsigned* __restrict__ curout,
                                unsigned* __restrict__ in_list, unsigned* __restrict__ out_list){
  int e = blockIdx.x*256 + threadIdx.x;
  unsigned s = (unsigned)ei[e], d = (unsigned)ei[NE+e];
  unsigned p = atomicAdd(&curin[d], 1u);  in_list[p] = s;
  unsigned q = atomicAdd(&curout[s], 1u); out_list[q] = d | (keep[e]<<31);
}
__global__ void selfbits_k(unsigned* __restrict__ bits){
  int i = blockIdx.x*256 + threadIdx.x;
  bits[i*128 + (i>>5)] = (1u << (i&31));
}
__global__ void edgebits_k(const int* __restrict__ ei, unsigned* __restrict__ bits){
  int e = blockIdx.x*256 + threadIdx.x;
  unsigned s = (unsigned)ei[e], d = (unsigned)ei[NE+e];
  atomicOr(&bits[d*128 + (s>>5)], 1u << (s&31));
}

// ---------------- 2-hop reach bitsets + counts ----------------
__global__ void reach_k(const unsigned* __restrict__ bits, const unsigned* __restrict__ in_off,
                        const unsigned* __restrict__ in_list, const unsigned* __restrict__ indeg,
                        unsigned* __restrict__ reach){
  int i = blockIdx.x, t = threadIdx.x;   // 128 threads
  unsigned off = in_off[i], deg = indeg[i];
  unsigned acc = bits[i*128 + t];
  for (unsigned j=0;j<deg;j++) acc |= bits[in_list[off+j]*128 + t];
  reach[i*128 + t] = acc;
}
__global__ void cnt_k(const unsigned* __restrict__ reach, float* __restrict__ cntinv){
  int i = blockIdx.x, l = threadIdx.x;   // 64 threads
  int c = __popc(reach[i*128 + l]) + __popc(reach[i*128 + 64 + l]);
  for (int o=32;o>0;o>>=1) c += __shfl_xor(c, o, 64);
  if (l==0) cntinv[i] = 1.0f / (float)c;
}

// ---------------- conversions ----------------
__global__ void cvt_bf16_k(const float* __restrict__ src, unsigned short* __restrict__ dst){
  int i = blockIdx.x*256 + threadIdx.x;          // 4 elems per thread
  float4 f = ((const float4*)src)[i];
  uint2 o;
  o.x = (unsigned)bf16rne(f.x) | ((unsigned)bf16rne(f.y)<<16);
  o.y = (unsigned)bf16rne(f.z) | ((unsigned)bf16rne(f.w)<<16);
  ((uint2*)dst)[i] = o;
}
// transpose+convert: src f32 [R][C] -> dst bf16 [C][R]; grid (C/64, R/64), 256 thr
__global__ void cvt_t_k(const float* __restrict__ src, unsigned short* __restrict__ dst,
                        int R, int C){
  __shared__ unsigned short tile[64][72];
  int t = threadIdx.x;
  int r0 = blockIdx.y*64, c0 = blockIdx.x*64;
  int tr = t>>2, tc = (t&3)*16;
  #pragma unroll
  for (int u=0;u<16;u++)
    tile[tr][tc+u] = bf16rne(src[(size_t)(r0+tr)*C + c0 + tc + u]);
  __syncthreads();
  unsigned short v[16];
  #pragma unroll
  for (int u=0;u<16;u++) v[u] = tile[tc+u][tr];
  uint4* vv = (uint4*)v;
  uint4* o = (uint4*)&dst[(size_t)(c0+tr)*R + r0 + tc];
  o[0] = vv[0]; o[1] = vv[1];
}

// ---------------- ego GEMM: ego_bf[i][f] = bf16( (reach@x_bf)[i][f] * cntinv[i] ) ----------------
// A from reach bits (in-register expansion), B from xT_bf [DIN][NN] (pre-transposed).
// tile 64m x 64n, 256 thr = 4 waves; wave w -> rows 16w..16w+15, 4 n-frags.
__global__ void bitgemm_k(const unsigned* __restrict__ reach, const unsigned short* __restrict__ xT,
                          const float* __restrict__ cntinv, unsigned short* __restrict__ ego_bf){
  __shared__ __align__(16) unsigned short bt[64*32];
  int t = threadIdx.x, w = t>>6, l = t&63;
  int m0 = blockIdx.x*64, n0 = blockIdx.y*64;
  int srow = t>>2, sg = t&3;
  int arow = m0 + 16*w + (l&15);
  int lg = l>>4;
  f32x4 acc[4];
  #pragma unroll
  for (int c=0;c<4;c++) acc[c] = f32x4{0.f,0.f,0.f,0.f};

  for (int kk=0; kk<NN; kk+=32){
    __syncthreads();
    // stage BT tile: rows n0..n0+63 of xT, k kk..kk+31 (XOR-swizzled 16B slots)
    {
      uint4 vsrc = *(const uint4*)&xT[(size_t)(n0+srow)*NN + kk + sg*8];
      *(uint4*)&bt[srow*32 + ((sg ^ (srow&3))*8)] = vsrc;
    }
    __syncthreads();
    // A-frag: expand 8 bits (k = kk+8*lg+j) of reach row
    unsigned word = reach[(size_t)arow*128 + (kk>>5)];
    unsigned byte = (word >> (8*lg)) & 0xFFu;
    union { short8 s; unsigned u[4]; } af;
    #pragma unroll
    for (int p=0;p<4;p++){
      unsigned b0 = (byte>>(2*p))&1u, b1 = (byte>>(2*p+1))&1u;
      af.u[p] = b0*0x3F80u | b1*0x3F800000u;
    }
    #pragma unroll
    for (int c=0;c<4;c++){
      int brow = 16*c + (l&15);
      short8 bf = *(const short8*)&bt[brow*32 + ((lg ^ (brow&3))*8)];
      acc[c] = __builtin_amdgcn_mfma_f32_16x16x32_bf16(af.s, bf, acc[c], 0,0,0);
    }
  }
  // epilogue: D row=(l>>4)*4+r, col=l&15 within each 16x16 frag
  float ci[4];
  #pragma unroll
  for (int r=0;r<4;r++) ci[r] = cntinv[m0 + 16*w + 4*lg + r];
  #pragma unroll
  for (int c=0;c<4;c++){
    #pragma unroll
    for (int r=0;r<4;r++){
      int row = m0 + 16*w + 4*lg + r;
      int col = n0 + 16*c + (l&15);
      ego_bf[(size_t)row*DIN + col] = bf16rne(acc[c][r] * ci[r]);
    }
  }
}

// ---------------- encoder GEMM: C f32[4096][512] = A_bf[4096][256] @ W_bf[256][512] + b ----------------
// BT = WT_bf [512][256] pre-transposed. tile 64x64, grid (8, 64).
__global__ void gemm_bf16_k(const unsigned short* __restrict__ A, const unsigned short* __restrict__ BT,
                            const float* __restrict__ bias, float* __restrict__ C){
  __shared__ __align__(16) unsigned short at[64*32];
  __shared__ __align__(16) unsigned short bt[64*32];
  int t = threadIdx.x, w = t>>6, l = t&63;
  int n0 = blockIdx.x*64, m0 = blockIdx.y*64;
  int srow = t>>2, sg = t&3;
  int lg = l>>4;
  f32x4 acc[4];
  #pragma unroll
  for (int c=0;c<4;c++) acc[c] = f32x4{0.f,0.f,0.f,0.f};

  for (int kk=0; kk<DIN; kk+=32){
    __syncthreads();
    {
      uint4 va = *(const uint4*)&A [(size_t)(m0+srow)*DIN + kk + sg*8];
      uint4 vb = *(const uint4*)&BT[(size_t)(n0+srow)*DIN + kk + sg*8];
      *(uint4*)&at[srow*32 + ((sg ^ (srow&3))*8)] = va;
      *(uint4*)&bt[srow*32 + ((sg ^ (srow&3))*8)] = vb;
    }
    __syncthreads();
    int ar = 16*w + (l&15);
    short8 af = *(const short8*)&at[ar*32 + ((lg ^ (ar&3))*8)];
    #pragma unroll
    for (int c=0;c<4;c++){
      int brow = 16*c + (l&15);
      short8 bf = *(const short8*)&bt[brow*32 + ((lg ^ (brow&3))*8)];
      acc[c] = __builtin_amdgcn_mfma_f32_16x16x32_bf16(af, bf, acc[c], 0,0,0);
    }
  }
  #pragma unroll
  for (int c=0;c<4;c++){
    #pragma unroll
    for (int r=0;r<4;r++){
      int row = m0 + 16*w + 4*lg + r;
      int col = n0 + 16*c + (l&15);
      C[(size_t)row*DHID + col] = acc[c][r] + bias[col];
    }
  }
}

// ---------------- cut feature (bf16 out) ----------------
__global__ void cut_k(const float* __restrict__ x, const unsigned* __restrict__ out_off,
                      const unsigned* __restrict__ outdeg, const unsigned* __restrict__ out_list,
                      unsigned short* __restrict__ cut_bf){
  int s = blockIdx.x, t = threadIdx.x;
  unsigned off = out_off[s], deg = outdeg[s];
  float acc = 0.f; int cnt = 0;
  for (unsigned j=0;j<deg;j++){
    unsigned p = out_list[off+j];
    if (p >> 31){ cnt++; acc += x[(p & 0xFFFFu)*DIN + t]; }
  }
  float v = cnt ? acc / (float)cnt : x[s*DIN + t];
  cut_bf[(size_t)s*DIN + t] = bf16rne(v);
}

// ---------------- fused: agg(in-edges) -> relu -> @fcW_block -> out ----------------
template<int ADDBIAS>
__global__ void aggfc_k(const float* __restrict__ h, const unsigned* __restrict__ in_off,
                        const unsigned* __restrict__ indeg, const unsigned* __restrict__ in_list,
                        const float* __restrict__ fcW, const float* __restrict__ fcb,
                        float* __restrict__ out){
  __shared__ float row[DHID];
  int i = blockIdx.x, t = threadIdx.x;
  unsigned off = in_off[i], deg = indeg[i];
  float a0=0.f, a1=0.f;
  for (unsigned j=0;j<deg;j++){
    unsigned s = in_list[off+j];
    a0 += h[(size_t)s*DHID + t];
    a1 += h[(size_t)s*DHID + t + 256];
  }
  row[t]     = fmaxf(a0, 0.f);
  row[t+256] = fmaxf(a1, 0.f);
  __syncthreads();
  if (t < DOUT){
    float acc = ADDBIAS ? fcb[t] : 0.f;
    for (int k=0;k<DHID;k++) acc += row[k] * fcW[k*DOUT + t];
    if (ADDBIAS) out[i*DOUT + t] = acc;
    else         out[i*DOUT + t] += acc;
  }
}

// ---------------- glob branch: henc row @ fcW_block -> out += (256 threads!) ----------------
__global__ void globfc_k(const float* __restrict__ h, const float* __restrict__ fcW,
                         float* __restrict__ out){
  __shared__ float row[DHID];
  int i = blockIdx.x, t = threadIdx.x;
  row[t]     = h[(size_t)i*DHID + t];
  row[t+256] = h[(size_t)i*DHID + t + 256];
  __syncthreads();
  if (t < DOUT){
    float acc = 0.f;
    for (int k=0;k<DHID;k++) acc += row[k] * fcW[k*DOUT + t];
    out[i*DOUT + t] += acc;
  }
}

// ---------------- log_softmax ----------------
__global__ void logsoftmax_k(float* __restrict__ out){
  int i = blockIdx.x, l = threadIdx.x;
  float v = out[i*DOUT + l];
  float m = v;
  for (int o=32;o>0;o>>=1) m = fmaxf(m, __shfl_xor(m, o, 64));
  float e = __expf(v - m), s = e;
  for (int o=32;o>0;o>>=1) s += __shfl_xor(s, o, 64);
  out[i*DOUT + l] = (v - m) - logf(s);
}

// ---------------- host launch ----------------
static inline size_t alignup(size_t x){ return (x + 255) & ~(size_t)255; }

extern "C" void kernel_launch(void* const* d_in, const int* in_sizes, int n_in,
                              void* d_out, int out_size, void* d_ws, size_t ws_size,
                              hipStream_t stream) {
  const float* x      = (const float*)d_in[0];
  const int*   ei     = (const int*)  d_in[1];
  const float* ego_W  = (const float*)d_in[2];
  const float* ego_b  = (const float*)d_in[3];
  const float* cut_W  = (const float*)d_in[4];
  const float* cut_b  = (const float*)d_in[5];
  const float* glob_W = (const float*)d_in[6];
  const float* glob_b = (const float*)d_in[7];
  const float* fc_W   = (const float*)d_in[8];
  const float* fc_b   = (const float*)d_in[9];
  float* out = (float*)d_out;

  // ---- workspace (~22.5 MB peak) ----
  char* base = (char*)d_ws;
  char* p = base;
  #define ALLOC(ty, name, cnt) ty* name = (ty*)p; p += alignup(sizeof(ty)*(size_t)(cnt));
  ALLOC(float,          henc,    (size_t)NN*DHID);  // 8MB; sort temps overlaid (dead before 1st gemm)
  ALLOC(unsigned,       keep,    NE);
  ALLOC(unsigned,       indeg,   NN);
  ALLOC(unsigned,       outdeg,  NN);
  ALLOC(unsigned,       in_off,  NN);
  ALLOC(unsigned,       out_off, NN);
  ALLOC(unsigned,       curin,   NN);
  ALLOC(unsigned,       curout,  NN);
  ALLOC(unsigned,       in_list, NE);
  ALLOC(unsigned,       out_list,NE);
  ALLOC(unsigned,       bits,    NN*128);
  ALLOC(unsigned,       reach,   NN*128);
  ALLOC(float,          cntinv,  NN);
  ALLOC(unsigned short, x_bf,    (size_t)NN*DIN);
  ALLOC(unsigned short, xT_bf,   (size_t)DIN*NN);
  ALLOC(unsigned short, ego_bf,  (size_t)NN*DIN);
  ALLOC(unsigned short, cut_bf,  (size_t)NN*DIN);
  ALLOC(unsigned short, egoWT,   (size_t)DHID*DIN);
  ALLOC(unsigned short, cutWT,   (size_t)DHID*DIN);
  ALLOC(unsigned short, globWT,  (size_t)DHID*DIN);
  #undef ALLOC
  size_t need = (size_t)(p - base);
  if (ws_size < need){
    hipMemsetAsync(d_out, 0x7F, (size_t)out_size*sizeof(float), stream);
    return;
  }
  char* q = (char*)henc;
  #define OALLOC(ty, name, cnt) ty* name = (ty*)q; q += alignup(sizeof(ty)*(size_t)(cnt));
  OALLOC(unsigned, keys1,  NE);
  OALLOC(unsigned, keys2,  NE);
  OALLOC(unsigned, rank1,  NE);
  OALLOC(unsigned, slow,   NE);
  OALLOC(unsigned, stb,    NE);
  OALLOC(unsigned, hist,   NBINS);
  OALLOC(unsigned, prefix, NBINS);
  OALLOC(unsigned, cursor, NBINS);
  OALLOC(unsigned, bsum,   256);
  #undef OALLOC

  const int EB = NE/256;

  auto scan = [&](unsigned* data, int n){
    int nb = n/256;
    hipLaunchKernelGGL(scan_local, dim3(nb), dim3(256), 0, stream, data, bsum);
    hipLaunchKernelGGL(scan_single, dim3(1), dim3(256), 0, stream, bsum, nb);
    hipLaunchKernelGGL(scan_addoff, dim3(nb), dim3(256), 0, stream, data, bsum);
  };

  // ---- keep mask ----
  hipLaunchKernelGGL(gen_keys, dim3(EB), dim3(256), 0, stream, keys1, keys2);
  hipMemsetAsync(hist, 0, NBINS*4, stream);
  hipLaunchKernelGGL(hist1_k, dim3(EB), dim3(256), 0, stream, keys1, hist);
  hipMemcpyAsync(prefix, hist, NBINS*4, hipMemcpyDeviceToDevice, stream);
  scan(prefix, NBINS);
  hipMemcpyAsync(cursor, prefix, NBINS*4, hipMemcpyDeviceToDevice, stream);
  hipLaunchKernelGGL(scat1_k, dim3(EB), dim3(256), 0, stream, keys1, cursor, slow, stb);
  hipLaunchKernelGGL(rank1_k, dim3(EB), dim3(256), 0, stream, keys1, prefix, hist, slow, stb, rank1);
  hipMemsetAsync(hist, 0, NBINS*4, stream);
  hipLaunchKernelGGL(hist2_k, dim3(EB), dim3(256), 0, stream, keys2, rank1, hist);
  hipMemcpyAsync(prefix, hist, NBINS*4, hipMemcpyDeviceToDevice, stream);
  scan(prefix, NBINS);
  hipMemcpyAsync(cursor, prefix, NBINS*4, hipMemcpyDeviceToDevice, stream);
  hipLaunchKernelGGL(scat2_k, dim3(EB), dim3(256), 0, stream, keys2, rank1, cursor, slow, stb);
  hipLaunchKernelGGL(rank2_k, dim3(EB), dim3(256), 0, stream, keys2, rank1, prefix, hist, slow, stb, keep);

  // ---- CSR ----
  hipMemsetAsync(indeg,  0, NN*4, stream);
  hipMemsetAsync(outdeg, 0, NN*4, stream);
  hipLaunchKernelGGL(degrees_k, dim3(EB), dim3(256), 0, stream, ei, indeg, outdeg);
  hipMemcpyAsync(in_off,  indeg,  NN*4, hipMemcpyDeviceToDevice, stream);
  hipMemcpyAsync(out_off, outdeg, NN*4, hipMemcpyDeviceToDevice, stream);
  scan(in_off, NN);
  scan(out_off, NN);
  hipMemcpyAsync(curin,  in_off,  NN*4, hipMemcpyDeviceToDevice, stream);
  hipMemcpyAsync(curout, out_off, NN*4, hipMemcpyDeviceToDevice, stream);
  hipLaunchKernelGGL(scatter_edges_k, dim3(EB), dim3(256), 0, stream, ei, keep, curin, curout, in_list, out_list);

  // ---- one-hop bitsets -> 2-hop reach -> counts ----
  hipMemsetAsync(bits, 0, (size_t)NN*128*4, stream);
  hipLaunchKernelGGL(selfbits_k, dim3(NN/256), dim3(256), 0, stream, bits);
  hipLaunchKernelGGL(edgebits_k, dim3(EB), dim3(256), 0, stream, ei, bits);
  hipLaunchKernelGGL(reach_k, dim3(NN), dim3(128), 0, stream, bits, in_off, in_list, indeg, reach);
  hipLaunchKernelGGL(cnt_k, dim3(NN), dim3(64), 0, stream, reach, cntinv);

  // ---- bf16 conversions / transposes ----
  hipLaunchKernelGGL(cvt_bf16_k, dim3((NN*DIN/4)/256), dim3(256), 0, stream, x, x_bf);
  hipLaunchKernelGGL(cvt_t_k, dim3(DIN/64, NN/64), dim3(256), 0, stream, x, xT_bf, NN, DIN);
  hipLaunchKernelGGL(cvt_t_k, dim3(DHID/64, DIN/64), dim3(256), 0, stream, ego_W,  egoWT,  DIN, DHID);
  hipLaunchKernelGGL(cvt_t_k, dim3(DHID/64, DIN/64), dim3(256), 0, stream, cut_W,  cutWT,  DIN, DHID);
  hipLaunchKernelGGL(cvt_t_k, dim3(DHID/64, DIN/64), dim3(256), 0, stream, glob_W, globWT, DIN, DHID);

  // ---- features ----
  hipLaunchKernelGGL(bitgemm_k, dim3(NN/64, DIN/64), dim3(256), 0, stream, reach, xT_bf, cntinv, ego_bf);
  hipLaunchKernelGGL(cut_k, dim3(NN), dim3(256), 0, stream, x, out_off, outdeg, out_list, cut_bf);

  // ---- branch 1: ego ----
  hipLaunchKernelGGL(gemm_bf16_k, dim3(DHID/64, NN/64), dim3(256), 0, stream, ego_bf, egoWT, ego_b, henc);
  hipLaunchKernelGGL((aggfc_k<1>), dim3(NN), dim3(256), 0, stream,
                     henc, in_off, indeg, in_list, fc_W, fc_b, out);
  // ---- branch 2: cut ----
  hipLaunchKernelGGL(gemm_bf16_k, dim3(DHID/64, NN/64), dim3(256), 0, stream, cut_bf, cutWT, cut_b, henc);
  hipLaunchKernelGGL((aggfc_k<0>), dim3(NN), dim3(256), 0, stream,
                     henc, in_off, indeg, in_list, fc_W + (size_t)DHID*DOUT, fc_b, out);
  // ---- branch 3: glob ----
  hipLaunchKernelGGL(gemm_bf16_k, dim3(DHID/64, NN/64), dim3(256), 0, stream, x_bf, globWT, glob_b, henc);
  hipLaunchKernelGGL(globfc_k, dim3(NN), dim3(256), 0, stream,
                     henc, fc_W + (size_t)2*DHID*DOUT, out);

  hipLaunchKernelGGL(logsoftmax_k, dim3(NN), dim3(64), 0, stream, out);
}

// Round 6
// 362.071 us; speedup vs baseline: 2.0599x; 1.0933x over previous
//
#include <hip/hip_runtime.h>

#define NN 4096
#define NE 131072
#define DIN 256
#define DHID 512
#define DOUT 64
#define DCAT 1536
#define NBINS 65536
#define HALF_E 65536

typedef __attribute__((ext_vector_type(8))) short short8;
typedef __attribute__((ext_vector_type(4))) float f32x4;

__device__ inline unsigned short bf16rne(float f){
  unsigned u = __float_as_uint(f);
  unsigned r = u + 0x7FFFu + ((u>>16)&1u);
  return (unsigned short)(r>>16);
}
__device__ inline float bf2f(unsigned short u){ return __uint_as_float(((unsigned)u)<<16); }

// ---------------- Threefry-2x32 (JAX-compatible) ----------------
struct K2 { unsigned a, b; };
__host__ __device__ constexpr unsigned rotl32(unsigned x, unsigned d){ return (x<<d)|(x>>(32u-d)); }
__host__ __device__ constexpr K2 tf2x32(unsigned k0, unsigned k1, unsigned x0, unsigned x1){
  unsigned k2 = k0 ^ k1 ^ 0x1BD11BDAu;
  x0 += k0; x1 += k1;
  x0+=x1; x1=rotl32(x1,13); x1^=x0;
  x0+=x1; x1=rotl32(x1,15); x1^=x0;
  x0+=x1; x1=rotl32(x1,26); x1^=x0;
  x0+=x1; x1=rotl32(x1, 6); x1^=x0;
  x0+=k1; x1+=k2+1u;
  x0+=x1; x1=rotl32(x1,17); x1^=x0;
  x0+=x1; x1=rotl32(x1,29); x1^=x0;
  x0+=x1; x1=rotl32(x1,16); x1^=x0;
  x0+=x1; x1=rotl32(x1,24); x1^=x0;
  x0+=k2; x1+=k0+2u;
  x0+=x1; x1=rotl32(x1,13); x1^=x0;
  x0+=x1; x1=rotl32(x1,15); x1^=x0;
  x0+=x1; x1=rotl32(x1,26); x1^=x0;
  x0+=x1; x1=rotl32(x1, 6); x1^=x0;
  x0+=k0; x1+=k1+3u;
  x0+=x1; x1=rotl32(x1,17); x1^=x0;
  x0+=x1; x1=rotl32(x1,29); x1^=x0;
  x0+=x1; x1=rotl32(x1,16); x1^=x0;
  x0+=x1; x1=rotl32(x1,24); x1^=x0;
  x0+=k1; x1+=k2+4u;
  x0+=x1; x1=rotl32(x1,13); x1^=x0;
  x0+=x1; x1=rotl32(x1,15); x1^=x0;
  x0+=x1; x1=rotl32(x1,26); x1^=x0;
  x0+=x1; x1=rotl32(x1, 6); x1^=x0;
  x0+=k2; x1+=k0+5u;
  return K2{x0,x1};
}
static_assert(tf2x32(0u,0u,0u,2u).a==4146024105u, "threefry mismatch o0");
static_assert(tf2x32(0u,0u,0u,2u).b==2718843009u, "threefry mismatch o1");
static_assert(tf2x32(0u,0u,1u,3u).a==967050713u,  "threefry mismatch o0b");
static_assert(tf2x32(0u,0u,1u,3u).b==1272950319u, "threefry mismatch o1b");

// partitionable threefry (verified passing r4/r5)
constexpr K2 E0 = tf2x32(0u,42u,0u,0u);     // key1
constexpr K2 E1 = tf2x32(0u,42u,0u,1u);     // sub1
constexpr unsigned SK1A = E1.a, SK1B = E1.b;
constexpr K2 F1 = tf2x32(E0.a,E0.b,0u,1u);  // sub2
constexpr unsigned SK2A = F1.a, SK2B = F1.b;

__global__ void gen_keys(unsigned* __restrict__ keys1, unsigned* __restrict__ keys2,
                         unsigned* __restrict__ hist1, unsigned* __restrict__ hist2){
  unsigned i = blockIdx.x*256u + threadIdx.x;
  K2 r1 = tf2x32(SK1A, SK1B, 0u, i);
  unsigned k1 = r1.a ^ r1.b;
  K2 r2 = tf2x32(SK2A, SK2B, 0u, i);
  unsigned k2 = r2.a ^ r2.b;
  keys1[i] = k1; keys2[i] = k2;
  atomicAdd(&hist1[k1>>16], 1u);
  atomicAdd(&hist2[k2>>16], 1u);
}

// ---------------- single-block dual exclusive scan (grid=2) ----------------
__global__ __launch_bounds__(1024) void scan1b_k(
    const unsigned* __restrict__ in0, unsigned* __restrict__ oA0, unsigned* __restrict__ oB0,
    const unsigned* __restrict__ in1, unsigned* __restrict__ oA1, unsigned* __restrict__ oB1, int n){
  const unsigned* in = blockIdx.x ? in1 : in0;
  unsigned* oA = blockIdx.x ? oA1 : oA0;
  unsigned* oB = blockIdx.x ? oB1 : oB0;
  int t = threadIdx.x;
  int per = n >> 10;
  unsigned s = 0;
  for (int j=0;j<per;j++) s += in[t*per+j];
  __shared__ unsigned ls[1024];
  ls[t] = s; __syncthreads();
  for (int off=1; off<1024; off<<=1){
    unsigned u = (t>=off)?ls[t-off]:0u; __syncthreads();
    ls[t]+=u; __syncthreads();
  }
  unsigned run = ls[t]-s;
  for (int j=0;j<per;j++){
    unsigned v = in[t*per+j];
    oA[t*per+j] = run; oB[t*per+j] = run;
    run += v;
  }
}

// ---------------- rank passes ----------------
__global__ void scat1_k(const unsigned* __restrict__ keys1, unsigned* __restrict__ cursor,
                        unsigned* __restrict__ slow, unsigned* __restrict__ stb){
  int e = blockIdx.x*256 + threadIdx.x;
  unsigned k = keys1[e];
  unsigned p = atomicAdd(&cursor[k>>16], 1u);
  slow[p] = k & 0xFFFFu; stb[p] = (unsigned)e;
}
__global__ void rank1_k(const unsigned* __restrict__ keys1, const unsigned* __restrict__ prefix,
                        const unsigned* __restrict__ hist, const unsigned* __restrict__ slow,
                        const unsigned* __restrict__ stb, unsigned* __restrict__ rank1){
  int e = blockIdx.x*256 + threadIdx.x;
  unsigned k = keys1[e], h = k>>16, lo = k & 0xFFFFu, tb = (unsigned)e;
  unsigned base = prefix[h], n = hist[h], r = 0;
  for (unsigned j=0;j<n;j++){
    unsigned l2 = slow[base+j], t2 = stb[base+j];
    if (l2 < lo || (l2==lo && t2 < tb)) r++;
  }
  rank1[e] = base + r;
}
__global__ void scat2_k(const unsigned* __restrict__ keys2, const unsigned* __restrict__ rank1,
                        unsigned* __restrict__ cursor, unsigned* __restrict__ slow, unsigned* __restrict__ stb){
  int e = blockIdx.x*256 + threadIdx.x;
  unsigned rk = rank1[e], k = keys2[rk];
  unsigned p = atomicAdd(&cursor[k>>16], 1u);
  slow[p] = k & 0xFFFFu; stb[p] = rk;
}
__global__ void rank2_k(const unsigned* __restrict__ keys2, const unsigned* __restrict__ rank1,
                        const unsigned* __restrict__ prefix, const unsigned* __restrict__ hist,
                        const unsigned* __restrict__ slow, const unsigned* __restrict__ stb,
                        unsigned* __restrict__ keep){
  int e = blockIdx.x*256 + threadIdx.x;
  unsigned rk = rank1[e], k = keys2[rk], h = k>>16, lo = k & 0xFFFFu;
  unsigned base = prefix[h], n = hist[h], r = 0;
  for (unsigned j=0;j<n;j++){
    unsigned l2 = slow[base+j], t2 = stb[base+j];
    if (l2 < lo || (l2==lo && t2 < rk)) r++;
  }
  keep[e] = (base + r >= HALF_E) ? 1u : 0u;
}

// ---------------- graph CSR ----------------
__global__ void degrees_k(const int* __restrict__ ei, unsigned* __restrict__ indeg, unsigned* __restrict__ outdeg){
  int e = blockIdx.x*256 + threadIdx.x;
  atomicAdd(&outdeg[ei[e]], 1u);
  atomicAdd(&indeg[ei[NE+e]], 1u);
}
__global__ void scatter_edges_k(const int* __restrict__ ei, const unsigned* __restrict__ keep,
                                unsigned* __restrict__ curin, unsigned* __restrict__ curout,
                                unsigned* __restrict__ in_list, unsigned* __restrict__ out_list){
  int e = blockIdx.x*256 + threadIdx.x;
  unsigned s = (unsigned)ei[e], d = (unsigned)ei[NE+e];
  unsigned p = atomicAdd(&curin[d], 1u);  in_list[p] = s;
  unsigned q = atomicAdd(&curout[s], 1u); out_list[q] = d | (keep[e]<<31);
}
__global__ void edgeself_k(const int* __restrict__ ei, unsigned* __restrict__ bits){
  int e = blockIdx.x*256 + threadIdx.x;
  unsigned s = (unsigned)ei[e], d = (unsigned)ei[NE+e];
  atomicOr(&bits[d*128 + (s>>5)], 1u << (s&31));
  if (e < NN) atomicOr(&bits[(unsigned)e*128 + ((unsigned)e>>5)], 1u << (e&31));
}

// ---------------- 2-hop reach + popcount (merged) ----------------
__global__ void reach_k(const unsigned* __restrict__ bits, const unsigned* __restrict__ in_off,
                        const unsigned* __restrict__ in_list, const unsigned* __restrict__ indeg,
                        unsigned* __restrict__ reach, float* __restrict__ cntinv){
  __shared__ int ws2[2];
  int i = blockIdx.x, t = threadIdx.x;   // 128 threads
  unsigned off = in_off[i], deg = indeg[i];
  unsigned acc = bits[i*128 + t];
  for (unsigned j=0;j<deg;j++) acc |= bits[in_list[off+j]*128 + t];
  reach[i*128 + t] = acc;
  int c = __popc(acc);
  for (int o=32;o>0;o>>=1) c += __shfl_xor(c, o, 64);
  if ((t&63)==0) ws2[t>>6] = c;
  __syncthreads();
  if (t==0) cntinv[i] = 1.0f / (float)(ws2[0]+ws2[1]);
}

// ---------------- conversions ----------------
__global__ void cvt_bf16_k(const float* __restrict__ src, unsigned short* __restrict__ dst){
  int i = blockIdx.x*256 + threadIdx.x;
  float4 f = ((const float4*)src)[i];
  uint2 o;
  o.x = (unsigned)bf16rne(f.x) | ((unsigned)bf16rne(f.y)<<16);
  o.y = (unsigned)bf16rne(f.z) | ((unsigned)bf16rne(f.w)<<16);
  ((uint2*)dst)[i] = o;
}
// x^T: f32 [NN][DIN] -> bf16 [DIN][NN]; grid (DIN/64, NN/64)
__global__ void cvtTx_k(const float* __restrict__ src, unsigned short* __restrict__ dst){
  __shared__ unsigned short tile[64][72];
  int t = threadIdx.x;
  int r0 = blockIdx.y*64, c0 = blockIdx.x*64;
  int tr = t>>2, tc = (t&3)*16;
  #pragma unroll
  for (int u=0;u<16;u++)
    tile[tr][tc+u] = bf16rne(src[(size_t)(r0+tr)*DIN + c0 + tc + u]);
  __syncthreads();
  unsigned short v[16];
  #pragma unroll
  for (int u=0;u<16;u++) v[u] = tile[tc+u][tr];
  uint4* vv = (uint4*)v;
  uint4* o = (uint4*)&dst[(size_t)(c0+tr)*NN + r0 + tc];
  o[0] = vv[0]; o[1] = vv[1];
}
// 4 weight transposes in one launch; z=0..2: [256][512]->[512][256]; z=3: fcW [1536][64]->[64][1536]
__global__ void cvtT4_k(const float* __restrict__ s0, unsigned short* __restrict__ d0,
                        const float* __restrict__ s1, unsigned short* __restrict__ d1,
                        const float* __restrict__ s2, unsigned short* __restrict__ d2,
                        const float* __restrict__ s3, unsigned short* __restrict__ d3){
  __shared__ unsigned short tile[64][72];
  int z = blockIdx.z;
  const float* src = z==0? s0 : z==1? s1 : z==2? s2 : s3;
  unsigned short* dst = z==0? d0 : z==1? d1 : z==2? d2 : d3;
  int R = (z<3)? DIN : DCAT;
  int C = (z<3)? DHID : DOUT;
  int r0 = blockIdx.y*64, c0 = blockIdx.x*64;
  if (r0 >= R || c0 >= C) return;
  int t = threadIdx.x;
  int tr = t>>2, tc = (t&3)*16;
  #pragma unroll
  for (int u=0;u<16;u++)
    tile[tr][tc+u] = bf16rne(src[(size_t)(r0+tr)*C + c0 + tc + u]);
  __syncthreads();
  unsigned short v[16];
  #pragma unroll
  for (int u=0;u<16;u++) v[u] = tile[tc+u][tr];
  uint4* vv = (uint4*)v;
  uint4* o = (uint4*)&dst[(size_t)(c0+tr)*R + r0 + tc];
  o[0] = vv[0]; o[1] = vv[1];
}

// ---------------- ego bit-GEMM, split-K=4, K_STEP=128 ----------------
__global__ void bitgemm_k(const unsigned* __restrict__ reach, const unsigned short* __restrict__ xT,
                          float* __restrict__ pbuf){
  __shared__ __align__(16) unsigned short bt[4][64*32];
  int t = threadIdx.x, w = t>>6, l = t&63;
  int m0 = blockIdx.x*64, n0 = blockIdx.y*64;
  int kbase = blockIdx.z*(NN/4);
  int srow = t>>2, sg = t&3;
  int arow = m0 + 16*w + (l&15);
  int lg = l>>4;
  f32x4 acc[4];
  #pragma unroll
  for (int c=0;c<4;c++) acc[c] = f32x4{0.f,0.f,0.f,0.f};

  for (int it=0; it<8; ++it){
    int kk = kbase + it*128;
    __syncthreads();
    #pragma unroll
    for (int s=0;s<4;s++){
      uint4 v = *(const uint4*)&xT[(size_t)(n0+srow)*NN + kk + 32*s + sg*8];
      *(uint4*)&bt[s][srow*32 + ((sg ^ (srow&3))*8)] = v;
    }
    __syncthreads();
    unsigned rw[4];
    *(uint4*)rw = *(const uint4*)&reach[(size_t)arow*128 + (kk>>5)];
    #pragma unroll
    for (int s=0;s<4;s++){
      unsigned byte = (rw[s] >> (8*lg)) & 0xFFu;
      union { short8 s8; unsigned u[4]; } af;
      #pragma unroll
      for (int pp=0;pp<4;pp++){
        unsigned b0 = (byte>>(2*pp))&1u, b1 = (byte>>(2*pp+1))&1u;
        af.u[pp] = b0*0x3F80u | b1*0x3F800000u;
      }
      #pragma unroll
      for (int c=0;c<4;c++){
        int brow = 16*c + (l&15);
        short8 bf = *(const short8*)&bt[s][brow*32 + ((lg ^ (brow&3))*8)];
        acc[c] = __builtin_amdgcn_mfma_f32_16x16x32_bf16(af.s8, bf, acc[c], 0,0,0);
      }
    }
  }
  size_t zoff = (size_t)blockIdx.z*NN*DIN;
  #pragma unroll
  for (int c=0;c<4;c++){
    #pragma unroll
    for (int r=0;r<4;r++){
      int row = m0 + 16*w + 4*lg + r;
      int col = n0 + 16*c + (l&15);
      pbuf[zoff + (size_t)row*DIN + col] = acc[c][r];
    }
  }
}

__global__ void redscale_k(const float* __restrict__ pbuf, const float* __restrict__ cntinv,
                           unsigned short* __restrict__ ego_bf){
  int g = blockIdx.x*256 + threadIdx.x;
  const size_t S = (size_t)NN*DIN/4;
  const float4* p4 = (const float4*)pbuf;
  float4 a = p4[g], b = p4[g+S], c = p4[g+2*S], d = p4[g+3*S];
  int row = (g*4)>>8;
  float ci = cntinv[row];
  float vx = (a.x+b.x+c.x+d.x)*ci, vy = (a.y+b.y+c.y+d.y)*ci;
  float vz = (a.z+b.z+c.z+d.z)*ci, vw = (a.w+b.w+c.w+d.w)*ci;
  uint2 o;
  o.x = (unsigned)bf16rne(vx) | ((unsigned)bf16rne(vy)<<16);
  o.y = (unsigned)bf16rne(vz) | ((unsigned)bf16rne(vw)<<16);
  ((uint2*)ego_bf)[g] = o;
}

// ---------------- cut feature (bf16 out) ----------------
__global__ void cut_k(const float* __restrict__ x, const unsigned* __restrict__ out_off,
                      const unsigned* __restrict__ outdeg, const unsigned* __restrict__ out_list,
                      unsigned short* __restrict__ cut_bf){
  int s = blockIdx.x, t = threadIdx.x;
  unsigned off = out_off[s], deg = outdeg[s];
  float acc = 0.f; int cnt = 0;
  for (unsigned j=0;j<deg;j++){
    unsigned p = out_list[off+j];
    if (p >> 31){ cnt++; acc += x[(p & 0xFFFFu)*DIN + t]; }
  }
  float v = cnt ? acc / (float)cnt : x[s*DIN + t];
  cut_bf[(size_t)s*DIN + t] = bf16rne(v);
}

// ---------------- aggregate 256-dim features over in-edges (linearity trick) ----------------
// segment_sum((feat@W+b)[src]) == (segment_sum feat[src])@W + indeg*b
__global__ void aggfeat_k(const unsigned short* __restrict__ ego_bf, const unsigned short* __restrict__ cut_bf,
                          const unsigned* __restrict__ in_off, const unsigned* __restrict__ indeg,
                          const unsigned* __restrict__ in_list,
                          unsigned short* __restrict__ aggE, unsigned short* __restrict__ aggC){
  int i = blockIdx.x, t = threadIdx.x;
  unsigned off = in_off[i], deg = indeg[i];
  float ae = 0.f, ac = 0.f;
  for (unsigned j=0;j<deg;j++){
    unsigned s = in_list[off+j];
    ae += bf2f(ego_bf[(size_t)s*DIN + t]);
    ac += bf2f(cut_bf[(size_t)s*DIN + t]);
  }
  aggE[(size_t)i*DIN + t] = bf16rne(ae);
  aggC[(size_t)i*DIN + t] = bf16rne(ac);
}

// ---------------- merged encoder GEMM (z: 0=ego-agg,1=cut-agg,2=glob) ----------------
__global__ void gemm3_k(const unsigned short* __restrict__ aggE, const unsigned short* __restrict__ aggC,
                        const unsigned short* __restrict__ xbf,
                        const unsigned short* __restrict__ WTe, const unsigned short* __restrict__ WTc,
                        const unsigned short* __restrict__ WTg,
                        const float* __restrict__ eb, const float* __restrict__ cb, const float* __restrict__ gb,
                        const unsigned* __restrict__ indeg, unsigned short* __restrict__ hcat){
  __shared__ __align__(16) unsigned short at[4][64*32];
  __shared__ __align__(16) unsigned short bt[4][64*32];
  int z = blockIdx.z;
  const unsigned short* A  = z==0? aggE : z==1? aggC : xbf;
  const unsigned short* BT = z==0? WTe  : z==1? WTc  : WTg;
  const float* bias        = z==0? eb   : z==1? cb   : gb;
  int t = threadIdx.x, w = t>>6, l = t&63;
  int n0 = blockIdx.x*64, m0 = blockIdx.y*64;
  int srow = t>>2, sg = t&3;
  int lg = l>>4;
  f32x4 acc[4];
  #pragma unroll
  for (int c=0;c<4;c++) acc[c] = f32x4{0.f,0.f,0.f,0.f};

  for (int it=0; it<2; ++it){
    int kk = it*128;
    __syncthreads();
    #pragma unroll
    for (int s=0;s<4;s++){
      uint4 va = *(const uint4*)&A [(size_t)(m0+srow)*DIN + kk + 32*s + sg*8];
      uint4 vb = *(const uint4*)&BT[(size_t)(n0+srow)*DIN + kk + 32*s + sg*8];
      *(uint4*)&at[s][srow*32 + ((sg ^ (srow&3))*8)] = va;
      *(uint4*)&bt[s][srow*32 + ((sg ^ (srow&3))*8)] = vb;
    }
    __syncthreads();
    int ar = 16*w + (l&15);
    #pragma unroll
    for (int s=0;s<4;s++){
      short8 af = *(const short8*)&at[s][ar*32 + ((lg ^ (ar&3))*8)];
      #pragma unroll
      for (int c=0;c<4;c++){
        int brow = 16*c + (l&15);
        short8 bf = *(const short8*)&bt[s][brow*32 + ((lg ^ (brow&3))*8)];
        acc[c] = __builtin_amdgcn_mfma_f32_16x16x32_bf16(af, bf, acc[c], 0,0,0);
      }
    }
  }
  #pragma unroll
  for (int c=0;c<4;c++){
    #pragma unroll
    for (int r=0;r<4;r++){
      int row = m0 + 16*w + 4*lg + r;
      int col = n0 + 16*c + (l&15);
      float scale = (z<2) ? (float)indeg[row] : 1.0f;
      float v = acc[c][r] + bias[col]*scale;
      if (z<2) v = fmaxf(v, 0.f);
      hcat[(size_t)row*DCAT + z*DHID + col] = bf16rne(v);
    }
  }
}

// ---------------- fc GEMM split-K=4: fcpart[kz] = hcat[:,kz*384:+384] @ fcW-block ----------------
__global__ void fcgemm_k(const unsigned short* __restrict__ hcat, const unsigned short* __restrict__ fcWT,
                         float* __restrict__ fcpart){
  __shared__ __align__(16) unsigned short at[4][64*32];
  __shared__ __align__(16) unsigned short bt[4][64*32];
  int t = threadIdx.x, w = t>>6, l = t&63;
  int m0 = blockIdx.x*64;
  int kbase = blockIdx.y*(DCAT/4);
  int srow = t>>2, sg = t&3;
  int lg = l>>4;
  f32x4 acc[4];
  #pragma unroll
  for (int c=0;c<4;c++) acc[c] = f32x4{0.f,0.f,0.f,0.f};

  for (int it=0; it<3; ++it){
    int kk = kbase + it*128;
    __syncthreads();
    #pragma unroll
    for (int s=0;s<4;s++){
      uint4 va = *(const uint4*)&hcat [(size_t)(m0+srow)*DCAT + kk + 32*s + sg*8];
      uint4 vb = *(const uint4*)&fcWT[(size_t)srow*DCAT + kk + 32*s + sg*8];
      *(uint4*)&at[s][srow*32 + ((sg ^ (srow&3))*8)] = va;
      *(uint4*)&bt[s][srow*32 + ((sg ^ (srow&3))*8)] = vb;
    }
    __syncthreads();
    int ar = 16*w + (l&15);
    #pragma unroll
    for (int s=0;s<4;s++){
      short8 af = *(const short8*)&at[s][ar*32 + ((lg ^ (ar&3))*8)];
      #pragma unroll
      for (int c=0;c<4;c++){
        int brow = 16*c + (l&15);
        short8 bf = *(const short8*)&bt[s][brow*32 + ((lg ^ (brow&3))*8)];
        acc[c] = __builtin_amdgcn_mfma_f32_16x16x32_bf16(af, bf, acc[c], 0,0,0);
      }
    }
  }
  size_t zoff = (size_t)blockIdx.y*NN*DOUT;
  #pragma unroll
  for (int c=0;c<4;c++){
    #pragma unroll
    for (int r=0;r<4;r++){
      int row = m0 + 16*w + 4*lg + r;
      int col = 16*c + (l&15);
      fcpart[zoff + (size_t)row*DOUT + col] = acc[c][r];
    }
  }
}

// ---------------- finish: sum partials + bias + log_softmax ----------------
__global__ void fcfin_k(const float* __restrict__ fcpart, const float* __restrict__ fcb,
                        float* __restrict__ out){
  int i = blockIdx.x, l = threadIdx.x;
  const size_t S = (size_t)NN*DOUT;
  size_t idx = (size_t)i*DOUT + l;
  float v = fcpart[idx] + fcpart[idx+S] + fcpart[idx+2*S] + fcpart[idx+3*S] + fcb[l];
  float m = v;
  for (int o=32;o>0;o>>=1) m = fmaxf(m, __shfl_xor(m, o, 64));
  float e = __expf(v - m), s = e;
  for (int o=32;o>0;o>>=1) s += __shfl_xor(s, o, 64);
  out[idx] = (v - m) - logf(s);
}

// ---------------- host launch ----------------
static inline size_t alignup(size_t x){ return (x + 255) & ~(size_t)255; }

extern "C" void kernel_launch(void* const* d_in, const int* in_sizes, int n_in,
                              void* d_out, int out_size, void* d_ws, size_t ws_size,
                              hipStream_t stream) {
  const float* x      = (const float*)d_in[0];
  const int*   ei     = (const int*)  d_in[1];
  const float* ego_W  = (const float*)d_in[2];
  const float* ego_b  = (const float*)d_in[3];
  const float* cut_W  = (const float*)d_in[4];
  const float* cut_b  = (const float*)d_in[5];
  const float* glob_W = (const float*)d_in[6];
  const float* glob_b = (const float*)d_in[7];
  const float* fc_W   = (const float*)d_in[8];
  const float* fc_b   = (const float*)d_in[9];
  float* out = (float*)d_out;

  char* base = (char*)d_ws;
  char* p = base;
  #define ALLOC(ty, name, cnt) ty* name = (ty*)p; p += alignup(sizeof(ty)*(size_t)(cnt));
  ALLOC(char,           R0,      (size_t)4*NN*DIN*4);   // 16MB: sort temps -> pbuf -> hcat
  ALLOC(unsigned,       keep,    NE);
  ALLOC(unsigned,       indeg,   NN);
  ALLOC(unsigned,       outdeg,  NN);
  ALLOC(unsigned,       in_off,  NN);
  ALLOC(unsigned,       out_off, NN);
  ALLOC(unsigned,       curin,   NN);
  ALLOC(unsigned,       curout,  NN);
  ALLOC(unsigned,       in_list, NE);
  ALLOC(unsigned,       out_list,NE);
  ALLOC(unsigned,       bits,    NN*128);
  ALLOC(unsigned,       reach,   NN*128);
  ALLOC(float,          cntinv,  NN);
  ALLOC(unsigned short, x_bf,    (size_t)NN*DIN);
  ALLOC(unsigned short, xT_bf,   (size_t)DIN*NN);
  ALLOC(unsigned short, ego_bf,  (size_t)NN*DIN);
  ALLOC(unsigned short, cut_bf,  (size_t)NN*DIN);
  ALLOC(unsigned short, aggE_bf, (size_t)NN*DIN);
  ALLOC(unsigned short, aggC_bf, (size_t)NN*DIN);
  ALLOC(unsigned short, egoWT,   (size_t)DHID*DIN);
  ALLOC(unsigned short, cutWT,   (size_t)DHID*DIN);
  ALLOC(unsigned short, globWT,  (size_t)DHID*DIN);
  ALLOC(unsigned short, fcWT,    (size_t)DOUT*DCAT);
  ALLOC(unsigned,       hist1,   NBINS);
  ALLOC(unsigned,       hist2,   NBINS);
  ALLOC(unsigned,       prefix1, NBINS);
  ALLOC(unsigned,       cursor1, NBINS);
  ALLOC(unsigned,       prefix2, NBINS);
  ALLOC(unsigned,       cursor2, NBINS);
  ALLOC(float,          fcpart,  (size_t)4*NN*DOUT);
  #undef ALLOC
  size_t need = (size_t)(p - base);
  if (ws_size < need){
    hipMemsetAsync(d_out, 0x7F, (size_t)out_size*sizeof(float), stream);
    return;
  }
  float*          pbuf = (float*)R0;
  unsigned short* hcat = (unsigned short*)R0;
  char* q = R0;
  #define OALLOC(ty, name, cnt) ty* name = (ty*)q; q += alignup(sizeof(ty)*(size_t)(cnt));
  OALLOC(unsigned, keys1,  NE);
  OALLOC(unsigned, keys2,  NE);
  OALLOC(unsigned, rank1,  NE);
  OALLOC(unsigned, slow,   NE);
  OALLOC(unsigned, stb,    NE);
  #undef OALLOC

  const int EB = NE/256;

  // ---- keep mask ----
  hipMemsetAsync(hist1, 0, 2*NBINS*4, stream);
  hipLaunchKernelGGL(gen_keys, dim3(EB), dim3(256), 0, stream, keys1, keys2, hist1, hist2);
  hipLaunchKernelGGL(scan1b_k, dim3(2), dim3(1024), 0, stream,
                     hist1, prefix1, cursor1, hist2, prefix2, cursor2, NBINS);
  hipLaunchKernelGGL(scat1_k, dim3(EB), dim3(256), 0, stream, keys1, cursor1, slow, stb);
  hipLaunchKernelGGL(rank1_k, dim3(EB), dim3(256), 0, stream, keys1, prefix1, hist1, slow, stb, rank1);
  hipLaunchKernelGGL(scat2_k, dim3(EB), dim3(256), 0, stream, keys2, rank1, cursor2, slow, stb);
  hipLaunchKernelGGL(rank2_k, dim3(EB), dim3(256), 0, stream, keys2, rank1, prefix2, hist2, slow, stb, keep);

  // ---- CSR ----
  hipMemsetAsync(indeg, 0, 2*NN*4, stream);
  hipLaunchKernelGGL(degrees_k, dim3(EB), dim3(256), 0, stream, ei, indeg, outdeg);
  hipLaunchKernelGGL(scan1b_k, dim3(2), dim3(1024), 0, stream,
                     indeg, in_off, curin, outdeg, out_off, curout, NN);
  hipLaunchKernelGGL(scatter_edges_k, dim3(EB), dim3(256), 0, stream,
                     ei, keep, curin, curout, in_list, out_list);

  // ---- bitsets -> reach(+cnt) ----
  hipMemsetAsync(bits, 0, (size_t)NN*128*4, stream);
  hipLaunchKernelGGL(edgeself_k, dim3(EB), dim3(256), 0, stream, ei, bits);
  hipLaunchKernelGGL(reach_k, dim3(NN), dim3(128), 0, stream,
                     bits, in_off, in_list, indeg, reach, cntinv);

  // ---- conversions ----
  hipLaunchKernelGGL(cvt_bf16_k, dim3((NN*DIN/4)/256), dim3(256), 0, stream, x, x_bf);
  hipLaunchKernelGGL(cvtTx_k, dim3(DIN/64, NN/64), dim3(256), 0, stream, x, xT_bf);
  hipLaunchKernelGGL(cvtT4_k, dim3(8, 24, 4), dim3(256), 0, stream,
                     ego_W, egoWT, cut_W, cutWT, glob_W, globWT, fc_W, fcWT);

  // ---- features ----
  hipLaunchKernelGGL(bitgemm_k, dim3(NN/64, DIN/64, 4), dim3(256), 0, stream, reach, xT_bf, pbuf);
  hipLaunchKernelGGL(redscale_k, dim3((NN*DIN/4)/256), dim3(256), 0, stream, pbuf, cntinv, ego_bf);
  hipLaunchKernelGGL(cut_k, dim3(NN), dim3(256), 0, stream, x, out_off, outdeg, out_list, cut_bf);
  hipLaunchKernelGGL(aggfeat_k, dim3(NN), dim3(256), 0, stream,
                     ego_bf, cut_bf, in_off, indeg, in_list, aggE_bf, aggC_bf);

  // ---- encoders (fused indeg*bias + relu -> bf16 concat) ----
  hipLaunchKernelGGL(gemm3_k, dim3(DHID/64, NN/64, 3), dim3(256), 0, stream,
                     aggE_bf, aggC_bf, x_bf, egoWT, cutWT, globWT,
                     ego_b, cut_b, glob_b, indeg, hcat);

  // ---- fc + log_softmax ----
  hipLaunchKernelGGL(fcgemm_k, dim3(NN/64, 4), dim3(256), 0, stream, hcat, fcWT, fcpart);
  hipLaunchKernelGGL(fcfin_k, dim3(NN), dim3(64), 0, stream, fcpart, fc_b, out);
}

// Round 7
// 234.107 us; speedup vs baseline: 3.1859x; 1.5466x over previous
//
#include <hip/hip_runtime.h>

#define NN 4096
#define NE 131072
#define DIN 256
#define DHID 512
#define DOUT 64
#define DCAT 1536
#define NBINS 65536
#define HALF_E 65536

typedef __attribute__((ext_vector_type(8))) short short8;
typedef __attribute__((ext_vector_type(4))) float f32x4;

__device__ inline unsigned short bf16rne(float f){
  unsigned u = __float_as_uint(f);
  unsigned r = u + 0x7FFFu + ((u>>16)&1u);
  return (unsigned short)(r>>16);
}
__device__ inline float bf2f(unsigned short u){ return __uint_as_float(((unsigned)u)<<16); }

// ---------------- Threefry-2x32 (JAX-compatible) ----------------
struct K2 { unsigned a, b; };
__host__ __device__ constexpr unsigned rotl32(unsigned x, unsigned d){ return (x<<d)|(x>>(32u-d)); }
__host__ __device__ constexpr K2 tf2x32(unsigned k0, unsigned k1, unsigned x0, unsigned x1){
  unsigned k2 = k0 ^ k1 ^ 0x1BD11BDAu;
  x0 += k0; x1 += k1;
  x0+=x1; x1=rotl32(x1,13); x1^=x0;
  x0+=x1; x1=rotl32(x1,15); x1^=x0;
  x0+=x1; x1=rotl32(x1,26); x1^=x0;
  x0+=x1; x1=rotl32(x1, 6); x1^=x0;
  x0+=k1; x1+=k2+1u;
  x0+=x1; x1=rotl32(x1,17); x1^=x0;
  x0+=x1; x1=rotl32(x1,29); x1^=x0;
  x0+=x1; x1=rotl32(x1,16); x1^=x0;
  x0+=x1; x1=rotl32(x1,24); x1^=x0;
  x0+=k2; x1+=k0+2u;
  x0+=x1; x1=rotl32(x1,13); x1^=x0;
  x0+=x1; x1=rotl32(x1,15); x1^=x0;
  x0+=x1; x1=rotl32(x1,26); x1^=x0;
  x0+=x1; x1=rotl32(x1, 6); x1^=x0;
  x0+=k0; x1+=k1+3u;
  x0+=x1; x1=rotl32(x1,17); x1^=x0;
  x0+=x1; x1=rotl32(x1,29); x1^=x0;
  x0+=x1; x1=rotl32(x1,16); x1^=x0;
  x0+=x1; x1=rotl32(x1,24); x1^=x0;
  x0+=k1; x1+=k2+4u;
  x0+=x1; x1=rotl32(x1,13); x1^=x0;
  x0+=x1; x1=rotl32(x1,15); x1^=x0;
  x0+=x1; x1=rotl32(x1,26); x1^=x0;
  x0+=x1; x1=rotl32(x1, 6); x1^=x0;
  x0+=k2; x1+=k0+5u;
  return K2{x0,x1};
}
static_assert(tf2x32(0u,0u,0u,2u).a==4146024105u, "threefry mismatch o0");
static_assert(tf2x32(0u,0u,0u,2u).b==2718843009u, "threefry mismatch o1");
static_assert(tf2x32(0u,0u,1u,3u).a==967050713u,  "threefry mismatch o0b");
static_assert(tf2x32(0u,0u,1u,3u).b==1272950319u, "threefry mismatch o1b");

// partitionable threefry (verified passing r4/r5)
constexpr K2 E0 = tf2x32(0u,42u,0u,0u);     // key1
constexpr K2 E1 = tf2x32(0u,42u,0u,1u);     // sub1
constexpr unsigned SK1A = E1.a, SK1B = E1.b;
constexpr K2 F1 = tf2x32(E0.a,E0.b,0u,1u);  // sub2
constexpr unsigned SK2A = F1.a, SK2B = F1.b;

__global__ void gen_keys(unsigned* __restrict__ keys1, unsigned* __restrict__ keys2,
                         unsigned* __restrict__ hist1, unsigned* __restrict__ hist2){
  unsigned i = blockIdx.x*256u + threadIdx.x;
  K2 r1 = tf2x32(SK1A, SK1B, 0u, i);
  unsigned k1 = r1.a ^ r1.b;
  K2 r2 = tf2x32(SK2A, SK2B, 0u, i);
  unsigned k2 = r2.a ^ r2.b;
  keys1[i] = k1; keys2[i] = k2;
  atomicAdd(&hist1[k1>>16], 1u);
  atomicAdd(&hist2[k2>>16], 1u);
}

// ---------------- 3-phase dual exclusive scan (multi-block, latency-friendly) ----------------
// phase A: per-block exclusive scan into oA; block totals into bsum[y][x]
__global__ void scanA_k(const unsigned* __restrict__ in0, const unsigned* __restrict__ in1,
                        unsigned* __restrict__ oA0, unsigned* __restrict__ oA1,
                        unsigned* __restrict__ bsum){
  const unsigned* in = blockIdx.y ? in1 : in0;
  unsigned* oA = blockIdx.y ? oA1 : oA0;
  __shared__ unsigned s[256];
  int t = threadIdx.x; unsigned i = blockIdx.x*256u + t;
  unsigned v = in[i]; s[t] = v; __syncthreads();
  for (int off=1; off<256; off<<=1){
    unsigned u = (t>=off)?s[t-off]:0u; __syncthreads();
    s[t]+=u; __syncthreads();
  }
  oA[i] = s[t]-v;
  if (t==255) bsum[blockIdx.y*gridDim.x + blockIdx.x] = s[255];
}
// phase B: exclusive scan of the nb block-sums (grid=2, one tensor each)
__global__ void scanB_k(unsigned* __restrict__ bsum, int nb){
  __shared__ unsigned s[256];
  int t = threadIdx.x;
  unsigned* b = bsum + blockIdx.x*nb;
  unsigned v = (t<nb)?b[t]:0u; s[t]=v; __syncthreads();
  for (int off=1; off<256; off<<=1){
    unsigned u=(t>=off)?s[t-off]:0u; __syncthreads();
    s[t]+=u; __syncthreads();
  }
  if (t<nb) b[t]=s[t]-v;
}
// phase C: add block offset; write BOTH outputs (prefix + cursor copies)
__global__ void scanC_k(unsigned* __restrict__ oA0, unsigned* __restrict__ oA1,
                        unsigned* __restrict__ oB0, unsigned* __restrict__ oB1,
                        const unsigned* __restrict__ bsum){
  unsigned* oA = blockIdx.y ? oA1 : oA0;
  unsigned* oB = blockIdx.y ? oB1 : oB0;
  unsigned i = blockIdx.x*256u + threadIdx.x;
  unsigned v = oA[i] + bsum[blockIdx.y*gridDim.x + blockIdx.x];
  oA[i]=v; oB[i]=v;
}

// ---------------- rank passes ----------------
__global__ void scat1_k(const unsigned* __restrict__ keys1, unsigned* __restrict__ cursor,
                        unsigned* __restrict__ slow, unsigned* __restrict__ stb){
  int e = blockIdx.x*256 + threadIdx.x;
  unsigned k = keys1[e];
  unsigned p = atomicAdd(&cursor[k>>16], 1u);
  slow[p] = k & 0xFFFFu; stb[p] = (unsigned)e;
}
__global__ void rank1_k(const unsigned* __restrict__ keys1, const unsigned* __restrict__ prefix,
                        const unsigned* __restrict__ hist, const unsigned* __restrict__ slow,
                        const unsigned* __restrict__ stb, unsigned* __restrict__ rank1){
  int e = blockIdx.x*256 + threadIdx.x;
  unsigned k = keys1[e], h = k>>16, lo = k & 0xFFFFu, tb = (unsigned)e;
  unsigned base = prefix[h], n = hist[h], r = 0;
  for (unsigned j=0;j<n;j++){
    unsigned l2 = slow[base+j], t2 = stb[base+j];
    if (l2 < lo || (l2==lo && t2 < tb)) r++;
  }
  rank1[e] = base + r;
}
__global__ void scat2_k(const unsigned* __restrict__ keys2, const unsigned* __restrict__ rank1,
                        unsigned* __restrict__ cursor, unsigned* __restrict__ slow, unsigned* __restrict__ stb){
  int e = blockIdx.x*256 + threadIdx.x;
  unsigned rk = rank1[e], k = keys2[rk];
  unsigned p = atomicAdd(&cursor[k>>16], 1u);
  slow[p] = k & 0xFFFFu; stb[p] = rk;
}
__global__ void rank2_k(const unsigned* __restrict__ keys2, const unsigned* __restrict__ rank1,
                        const unsigned* __restrict__ prefix, const unsigned* __restrict__ hist,
                        const unsigned* __restrict__ slow, const unsigned* __restrict__ stb,
                        unsigned* __restrict__ keep){
  int e = blockIdx.x*256 + threadIdx.x;
  unsigned rk = rank1[e], k = keys2[rk], h = k>>16, lo = k & 0xFFFFu;
  unsigned base = prefix[h], n = hist[h], r = 0;
  for (unsigned j=0;j<n;j++){
    unsigned l2 = slow[base+j], t2 = stb[base+j];
    if (l2 < lo || (l2==lo && t2 < rk)) r++;
  }
  keep[e] = (base + r >= HALF_E) ? 1u : 0u;
}

// ---------------- graph CSR ----------------
__global__ void degrees_k(const int* __restrict__ ei, unsigned* __restrict__ indeg, unsigned* __restrict__ outdeg){
  int e = blockIdx.x*256 + threadIdx.x;
  atomicAdd(&outdeg[ei[e]], 1u);
  atomicAdd(&indeg[ei[NE+e]], 1u);
}
__global__ void scatter_edges_k(const int* __restrict__ ei, const unsigned* __restrict__ keep,
                                unsigned* __restrict__ curin, unsigned* __restrict__ curout,
                                unsigned* __restrict__ in_list, unsigned* __restrict__ out_list){
  int e = blockIdx.x*256 + threadIdx.x;
  unsigned s = (unsigned)ei[e], d = (unsigned)ei[NE+e];
  unsigned p = atomicAdd(&curin[d], 1u);  in_list[p] = s;
  unsigned q = atomicAdd(&curout[s], 1u); out_list[q] = d | (keep[e]<<31);
}
__global__ void edgeself_k(const int* __restrict__ ei, unsigned* __restrict__ bits){
  int e = blockIdx.x*256 + threadIdx.x;
  unsigned s = (unsigned)ei[e], d = (unsigned)ei[NE+e];
  atomicOr(&bits[d*128 + (s>>5)], 1u << (s&31));
  if (e < NN) atomicOr(&bits[(unsigned)e*128 + ((unsigned)e>>5)], 1u << (e&31));
}

// ---------------- 2-hop reach + popcount (merged) ----------------
__global__ void reach_k(const unsigned* __restrict__ bits, const unsigned* __restrict__ in_off,
                        const unsigned* __restrict__ in_list, const unsigned* __restrict__ indeg,
                        unsigned* __restrict__ reach, float* __restrict__ cntinv){
  __shared__ int ws2[2];
  int i = blockIdx.x, t = threadIdx.x;   // 128 threads
  unsigned off = in_off[i], deg = indeg[i];
  unsigned acc = bits[i*128 + t];
  for (unsigned j=0;j<deg;j++) acc |= bits[in_list[off+j]*128 + t];
  reach[i*128 + t] = acc;
  int c = __popc(acc);
  for (int o=32;o>0;o>>=1) c += __shfl_xor(c, o, 64);
  if ((t&63)==0) ws2[t>>6] = c;
  __syncthreads();
  if (t==0) cntinv[i] = 1.0f / (float)(ws2[0]+ws2[1]);
}

// ---------------- conversions ----------------
__global__ void cvt_bf16_k(const float* __restrict__ src, unsigned short* __restrict__ dst){
  int i = blockIdx.x*256 + threadIdx.x;
  float4 f = ((const float4*)src)[i];
  uint2 o;
  o.x = (unsigned)bf16rne(f.x) | ((unsigned)bf16rne(f.y)<<16);
  o.y = (unsigned)bf16rne(f.z) | ((unsigned)bf16rne(f.w)<<16);
  ((uint2*)dst)[i] = o;
}
// x^T: f32 [NN][DIN] -> bf16 [DIN][NN]; grid (DIN/64, NN/64)
__global__ void cvtTx_k(const float* __restrict__ src, unsigned short* __restrict__ dst){
  __shared__ unsigned short tile[64][72];
  int t = threadIdx.x;
  int r0 = blockIdx.y*64, c0 = blockIdx.x*64;
  int tr = t>>2, tc = (t&3)*16;
  #pragma unroll
  for (int u=0;u<16;u++)
    tile[tr][tc+u] = bf16rne(src[(size_t)(r0+tr)*DIN + c0 + tc + u]);
  __syncthreads();
  unsigned short v[16];
  #pragma unroll
  for (int u=0;u<16;u++) v[u] = tile[tc+u][tr];
  uint4* vv = (uint4*)v;
  uint4* o = (uint4*)&dst[(size_t)(c0+tr)*NN + r0 + tc];
  o[0] = vv[0]; o[1] = vv[1];
}
// 4 weight transposes in one launch; z=0..2: [256][512]->[512][256]; z=3: fcW [1536][64]->[64][1536]
__global__ void cvtT4_k(const float* __restrict__ s0, unsigned short* __restrict__ d0,
                        const float* __restrict__ s1, unsigned short* __restrict__ d1,
                        const float* __restrict__ s2, unsigned short* __restrict__ d2,
                        const float* __restrict__ s3, unsigned short* __restrict__ d3){
  __shared__ unsigned short tile[64][72];
  int z = blockIdx.z;
  const float* src = z==0? s0 : z==1? s1 : z==2? s2 : s3;
  unsigned short* dst = z==0? d0 : z==1? d1 : z==2? d2 : d3;
  int R = (z<3)? DIN : DCAT;
  int C = (z<3)? DHID : DOUT;
  int r0 = blockIdx.y*64, c0 = blockIdx.x*64;
  if (r0 >= R || c0 >= C) return;
  int t = threadIdx.x;
  int tr = t>>2, tc = (t&3)*16;
  #pragma unroll
  for (int u=0;u<16;u++)
    tile[tr][tc+u] = bf16rne(src[(size_t)(r0+tr)*C + c0 + tc + u]);
  __syncthreads();
  unsigned short v[16];
  #pragma unroll
  for (int u=0;u<16;u++) v[u] = tile[tc+u][tr];
  uint4* vv = (uint4*)v;
  uint4* o = (uint4*)&dst[(size_t)(c0+tr)*R + r0 + tc];
  o[0] = vv[0]; o[1] = vv[1];
}

// ---------------- ego bit-GEMM, split-K=4, K_STEP=128 ----------------
__global__ void bitgemm_k(const unsigned* __restrict__ reach, const unsigned short* __restrict__ xT,
                          float* __restrict__ pbuf){
  __shared__ __align__(16) unsigned short bt[4][64*32];
  int t = threadIdx.x, w = t>>6, l = t&63;
  int m0 = blockIdx.x*64, n0 = blockIdx.y*64;
  int kbase = blockIdx.z*(NN/4);
  int srow = t>>2, sg = t&3;
  int arow = m0 + 16*w + (l&15);
  int lg = l>>4;
  f32x4 acc[4];
  #pragma unroll
  for (int c=0;c<4;c++) acc[c] = f32x4{0.f,0.f,0.f,0.f};

  for (int it=0; it<8; ++it){
    int kk = kbase + it*128;
    __syncthreads();
    #pragma unroll
    for (int s=0;s<4;s++){
      uint4 v = *(const uint4*)&xT[(size_t)(n0+srow)*NN + kk + 32*s + sg*8];
      *(uint4*)&bt[s][srow*32 + ((sg ^ (srow&3))*8)] = v;
    }
    __syncthreads();
    unsigned rw[4];
    *(uint4*)rw = *(const uint4*)&reach[(size_t)arow*128 + (kk>>5)];
    #pragma unroll
    for (int s=0;s<4;s++){
      unsigned byte = (rw[s] >> (8*lg)) & 0xFFu;
      union { short8 s8; unsigned u[4]; } af;
      #pragma unroll
      for (int pp=0;pp<4;pp++){
        unsigned b0 = (byte>>(2*pp))&1u, b1 = (byte>>(2*pp+1))&1u;
        af.u[pp] = b0*0x3F80u | b1*0x3F800000u;
      }
      #pragma unroll
      for (int c=0;c<4;c++){
        int brow = 16*c + (l&15);
        short8 bf = *(const short8*)&bt[s][brow*32 + ((lg ^ (brow&3))*8)];
        acc[c] = __builtin_amdgcn_mfma_f32_16x16x32_bf16(af.s8, bf, acc[c], 0,0,0);
      }
    }
  }
  size_t zoff = (size_t)blockIdx.z*NN*DIN;
  #pragma unroll
  for (int c=0;c<4;c++){
    #pragma unroll
    for (int r=0;r<4;r++){
      int row = m0 + 16*w + 4*lg + r;
      int col = n0 + 16*c + (l&15);
      pbuf[zoff + (size_t)row*DIN + col] = acc[c][r];
    }
  }
}

__global__ void redscale_k(const float* __restrict__ pbuf, const float* __restrict__ cntinv,
                           unsigned short* __restrict__ ego_bf){
  int g = blockIdx.x*256 + threadIdx.x;
  const size_t S = (size_t)NN*DIN/4;
  const float4* p4 = (const float4*)pbuf;
  float4 a = p4[g], b = p4[g+S], c = p4[g+2*S], d = p4[g+3*S];
  int row = (g*4)>>8;
  float ci = cntinv[row];
  float vx = (a.x+b.x+c.x+d.x)*ci, vy = (a.y+b.y+c.y+d.y)*ci;
  float vz = (a.z+b.z+c.z+d.z)*ci, vw = (a.w+b.w+c.w+d.w)*ci;
  uint2 o;
  o.x = (unsigned)bf16rne(vx) | ((unsigned)bf16rne(vy)<<16);
  o.y = (unsigned)bf16rne(vz) | ((unsigned)bf16rne(vw)<<16);
  ((uint2*)ego_bf)[g] = o;
}

// ---------------- cut feature (bf16 out) ----------------
__global__ void cut_k(const float* __restrict__ x, const unsigned* __restrict__ out_off,
                      const unsigned* __restrict__ outdeg, const unsigned* __restrict__ out_list,
                      unsigned short* __restrict__ cut_bf){
  int s = blockIdx.x, t = threadIdx.x;
  unsigned off = out_off[s], deg = outdeg[s];
  float acc = 0.f; int cnt = 0;
  for (unsigned j=0;j<deg;j++){
    unsigned p = out_list[off+j];
    if (p >> 31){ cnt++; acc += x[(p & 0xFFFFu)*DIN + t]; }
  }
  float v = cnt ? acc / (float)cnt : x[s*DIN + t];
  cut_bf[(size_t)s*DIN + t] = bf16rne(v);
}

// ---------------- aggregate 256-dim features over in-edges (linearity trick) ----------------
__global__ void aggfeat_k(const unsigned short* __restrict__ ego_bf, const unsigned short* __restrict__ cut_bf,
                          const unsigned* __restrict__ in_off, const unsigned* __restrict__ indeg,
                          const unsigned* __restrict__ in_list,
                          unsigned short* __restrict__ aggE, unsigned short* __restrict__ aggC){
  int i = blockIdx.x, t = threadIdx.x;
  unsigned off = in_off[i], deg = indeg[i];
  float ae = 0.f, ac = 0.f;
  for (unsigned j=0;j<deg;j++){
    unsigned s = in_list[off+j];
    ae += bf2f(ego_bf[(size_t)s*DIN + t]);
    ac += bf2f(cut_bf[(size_t)s*DIN + t]);
  }
  aggE[(size_t)i*DIN + t] = bf16rne(ae);
  aggC[(size_t)i*DIN + t] = bf16rne(ac);
}

// ---------------- merged encoder GEMM (z: 0=ego-agg,1=cut-agg,2=glob) ----------------
__global__ void gemm3_k(const unsigned short* __restrict__ aggE, const unsigned short* __restrict__ aggC,
                        const unsigned short* __restrict__ xbf,
                        const unsigned short* __restrict__ WTe, const unsigned short* __restrict__ WTc,
                        const unsigned short* __restrict__ WTg,
                        const float* __restrict__ eb, const float* __restrict__ cb, const float* __restrict__ gb,
                        const unsigned* __restrict__ indeg, unsigned short* __restrict__ hcat){
  __shared__ __align__(16) unsigned short at[4][64*32];
  __shared__ __align__(16) unsigned short bt[4][64*32];
  int z = blockIdx.z;
  const unsigned short* A  = z==0? aggE : z==1? aggC : xbf;
  const unsigned short* BT = z==0? WTe  : z==1? WTc  : WTg;
  const float* bias        = z==0? eb   : z==1? cb   : gb;
  int t = threadIdx.x, w = t>>6, l = t&63;
  int n0 = blockIdx.x*64, m0 = blockIdx.y*64;
  int srow = t>>2, sg = t&3;
  int lg = l>>4;
  f32x4 acc[4];
  #pragma unroll
  for (int c=0;c<4;c++) acc[c] = f32x4{0.f,0.f,0.f,0.f};

  for (int it=0; it<2; ++it){
    int kk = it*128;
    __syncthreads();
    #pragma unroll
    for (int s=0;s<4;s++){
      uint4 va = *(const uint4*)&A [(size_t)(m0+srow)*DIN + kk + 32*s + sg*8];
      uint4 vb = *(const uint4*)&BT[(size_t)(n0+srow)*DIN + kk + 32*s + sg*8];
      *(uint4*)&at[s][srow*32 + ((sg ^ (srow&3))*8)] = va;
      *(uint4*)&bt[s][srow*32 + ((sg ^ (srow&3))*8)] = vb;
    }
    __syncthreads();
    int ar = 16*w + (l&15);
    #pragma unroll
    for (int s=0;s<4;s++){
      short8 af = *(const short8*)&at[s][ar*32 + ((lg ^ (ar&3))*8)];
      #pragma unroll
      for (int c=0;c<4;c++){
        int brow = 16*c + (l&15);
        short8 bf = *(const short8*)&bt[s][brow*32 + ((lg ^ (brow&3))*8)];
        acc[c] = __builtin_amdgcn_mfma_f32_16x16x32_bf16(af, bf, acc[c], 0,0,0);
      }
    }
  }
  #pragma unroll
  for (int c=0;c<4;c++){
    #pragma unroll
    for (int r=0;r<4;r++){
      int row = m0 + 16*w + 4*lg + r;
      int col = n0 + 16*c + (l&15);
      float scale = (z<2) ? (float)indeg[row] : 1.0f;
      float v = acc[c][r] + bias[col]*scale;
      if (z<2) v = fmaxf(v, 0.f);
      hcat[(size_t)row*DCAT + z*DHID + col] = bf16rne(v);
    }
  }
}

// ---------------- fc GEMM split-K=4 ----------------
__global__ void fcgemm_k(const unsigned short* __restrict__ hcat, const unsigned short* __restrict__ fcWT,
                         float* __restrict__ fcpart){
  __shared__ __align__(16) unsigned short at[4][64*32];
  __shared__ __align__(16) unsigned short bt[4][64*32];
  int t = threadIdx.x, w = t>>6, l = t&63;
  int m0 = blockIdx.x*64;
  int kbase = blockIdx.y*(DCAT/4);
  int srow = t>>2, sg = t&3;
  int lg = l>>4;
  f32x4 acc[4];
  #pragma unroll
  for (int c=0;c<4;c++) acc[c] = f32x4{0.f,0.f,0.f,0.f};

  for (int it=0; it<3; ++it){
    int kk = kbase + it*128;
    __syncthreads();
    #pragma unroll
    for (int s=0;s<4;s++){
      uint4 va = *(const uint4*)&hcat [(size_t)(m0+srow)*DCAT + kk + 32*s + sg*8];
      uint4 vb = *(const uint4*)&fcWT[(size_t)srow*DCAT + kk + 32*s + sg*8];
      *(uint4*)&at[s][srow*32 + ((sg ^ (srow&3))*8)] = va;
      *(uint4*)&bt[s][srow*32 + ((sg ^ (srow&3))*8)] = vb;
    }
    __syncthreads();
    int ar = 16*w + (l&15);
    #pragma unroll
    for (int s=0;s<4;s++){
      short8 af = *(const short8*)&at[s][ar*32 + ((lg ^ (ar&3))*8)];
      #pragma unroll
      for (int c=0;c<4;c++){
        int brow = 16*c + (l&15);
        short8 bf = *(const short8*)&bt[s][brow*32 + ((lg ^ (brow&3))*8)];
        acc[c] = __builtin_amdgcn_mfma_f32_16x16x32_bf16(af, bf, acc[c], 0,0,0);
      }
    }
  }
  size_t zoff = (size_t)blockIdx.y*NN*DOUT;
  #pragma unroll
  for (int c=0;c<4;c++){
    #pragma unroll
    for (int r=0;r<4;r++){
      int row = m0 + 16*w + 4*lg + r;
      int col = 16*c + (l&15);
      fcpart[zoff + (size_t)row*DOUT + col] = acc[c][r];
    }
  }
}

// ---------------- finish: sum partials + bias + log_softmax ----------------
__global__ void fcfin_k(const float* __restrict__ fcpart, const float* __restrict__ fcb,
                        float* __restrict__ out){
  int i = blockIdx.x, l = threadIdx.x;
  const size_t S = (size_t)NN*DOUT;
  size_t idx = (size_t)i*DOUT + l;
  float v = fcpart[idx] + fcpart[idx+S] + fcpart[idx+2*S] + fcpart[idx+3*S] + fcb[l];
  float m = v;
  for (int o=32;o>0;o>>=1) m = fmaxf(m, __shfl_xor(m, o, 64));
  float e = __expf(v - m), s = e;
  for (int o=32;o>0;o>>=1) s += __shfl_xor(s, o, 64);
  out[idx] = (v - m) - logf(s);
}

// ---------------- host launch ----------------
static inline size_t alignup(size_t x){ return (x + 255) & ~(size_t)255; }

extern "C" void kernel_launch(void* const* d_in, const int* in_sizes, int n_in,
                              void* d_out, int out_size, void* d_ws, size_t ws_size,
                              hipStream_t stream) {
  const float* x      = (const float*)d_in[0];
  const int*   ei     = (const int*)  d_in[1];
  const float* ego_W  = (const float*)d_in[2];
  const float* ego_b  = (const float*)d_in[3];
  const float* cut_W  = (const float*)d_in[4];
  const float* cut_b  = (const float*)d_in[5];
  const float* glob_W = (const float*)d_in[6];
  const float* glob_b = (const float*)d_in[7];
  const float* fc_W   = (const float*)d_in[8];
  const float* fc_b   = (const float*)d_in[9];
  float* out = (float*)d_out;

  char* base = (char*)d_ws;
  char* p = base;
  #define ALLOC(ty, name, cnt) ty* name = (ty*)p; p += alignup(sizeof(ty)*(size_t)(cnt));
  ALLOC(char,           R0,      (size_t)4*NN*DIN*4);   // 16MB: sort temps -> pbuf -> hcat
  ALLOC(unsigned,       keep,    NE);
  ALLOC(unsigned,       indeg,   NN);
  ALLOC(unsigned,       outdeg,  NN);
  ALLOC(unsigned,       in_off,  NN);
  ALLOC(unsigned,       out_off, NN);
  ALLOC(unsigned,       curin,   NN);
  ALLOC(unsigned,       curout,  NN);
  ALLOC(unsigned,       in_list, NE);
  ALLOC(unsigned,       out_list,NE);
  ALLOC(unsigned,       bits,    NN*128);
  ALLOC(unsigned,       reach,   NN*128);
  ALLOC(float,          cntinv,  NN);
  ALLOC(unsigned short, x_bf,    (size_t)NN*DIN);
  ALLOC(unsigned short, xT_bf,   (size_t)DIN*NN);
  ALLOC(unsigned short, ego_bf,  (size_t)NN*DIN);
  ALLOC(unsigned short, cut_bf,  (size_t)NN*DIN);
  ALLOC(unsigned short, aggE_bf, (size_t)NN*DIN);
  ALLOC(unsigned short, aggC_bf, (size_t)NN*DIN);
  ALLOC(unsigned short, egoWT,   (size_t)DHID*DIN);
  ALLOC(unsigned short, cutWT,   (size_t)DHID*DIN);
  ALLOC(unsigned short, globWT,  (size_t)DHID*DIN);
  ALLOC(unsigned short, fcWT,    (size_t)DOUT*DCAT);
  ALLOC(unsigned,       hist1,   NBINS);
  ALLOC(unsigned,       hist2,   NBINS);
  ALLOC(unsigned,       prefix1, NBINS);
  ALLOC(unsigned,       cursor1, NBINS);
  ALLOC(unsigned,       prefix2, NBINS);
  ALLOC(unsigned,       cursor2, NBINS);
  ALLOC(unsigned,       bsum,    512);
  ALLOC(float,          fcpart,  (size_t)4*NN*DOUT);
  #undef ALLOC
  size_t need = (size_t)(p - base);
  if (ws_size < need){
    hipMemsetAsync(d_out, 0x7F, (size_t)out_size*sizeof(float), stream);
    return;
  }
  float*          pbuf = (float*)R0;
  unsigned short* hcat = (unsigned short*)R0;
  char* q = R0;
  #define OALLOC(ty, name, cnt) ty* name = (ty*)q; q += alignup(sizeof(ty)*(size_t)(cnt));
  OALLOC(unsigned, keys1,  NE);
  OALLOC(unsigned, keys2,  NE);
  OALLOC(unsigned, rank1,  NE);
  OALLOC(unsigned, slow,   NE);
  OALLOC(unsigned, stb,    NE);
  #undef OALLOC

  const int EB = NE/256;

  // ---- keep mask ----
  hipMemsetAsync(hist1, 0, 2*NBINS*4, stream);
  hipLaunchKernelGGL(gen_keys, dim3(EB), dim3(256), 0, stream, keys1, keys2, hist1, hist2);
  // dual scan of hist1/hist2 -> (prefix1,cursor1)/(prefix2,cursor2)
  hipLaunchKernelGGL(scanA_k, dim3(NBINS/256, 2), dim3(256), 0, stream,
                     hist1, hist2, prefix1, prefix2, bsum);
  hipLaunchKernelGGL(scanB_k, dim3(2), dim3(256), 0, stream, bsum, NBINS/256);
  hipLaunchKernelGGL(scanC_k, dim3(NBINS/256, 2), dim3(256), 0, stream,
                     prefix1, prefix2, cursor1, cursor2, bsum);
  hipLaunchKernelGGL(scat1_k, dim3(EB), dim3(256), 0, stream, keys1, cursor1, slow, stb);
  hipLaunchKernelGGL(rank1_k, dim3(EB), dim3(256), 0, stream, keys1, prefix1, hist1, slow, stb, rank1);
  hipLaunchKernelGGL(scat2_k, dim3(EB), dim3(256), 0, stream, keys2, rank1, cursor2, slow, stb);
  hipLaunchKernelGGL(rank2_k, dim3(EB), dim3(256), 0, stream, keys2, rank1, prefix2, hist2, slow, stb, keep);

  // ---- CSR ----
  hipMemsetAsync(indeg, 0, 2*NN*4, stream);
  hipLaunchKernelGGL(degrees_k, dim3(EB), dim3(256), 0, stream, ei, indeg, outdeg);
  hipLaunchKernelGGL(scanA_k, dim3(NN/256, 2), dim3(256), 0, stream,
                     indeg, outdeg, in_off, out_off, bsum);
  hipLaunchKernelGGL(scanB_k, dim3(2), dim3(256), 0, stream, bsum, NN/256);
  hipLaunchKernelGGL(scanC_k, dim3(NN/256, 2), dim3(256), 0, stream,
                     in_off, out_off, curin, curout, bsum);
  hipLaunchKernelGGL(scatter_edges_k, dim3(EB), dim3(256), 0, stream,
                     ei, keep, curin, curout, in_list, out_list);

  // ---- bitsets -> reach(+cnt) ----
  hipMemsetAsync(bits, 0, (size_t)NN*128*4, stream);
  hipLaunchKernelGGL(edgeself_k, dim3(EB), dim3(256), 0, stream, ei, bits);
  hipLaunchKernelGGL(reach_k, dim3(NN), dim3(128), 0, stream,
                     bits, in_off, in_list, indeg, reach, cntinv);

  // ---- conversions ----
  hipLaunchKernelGGL(cvt_bf16_k, dim3((NN*DIN/4)/256), dim3(256), 0, stream, x, x_bf);
  hipLaunchKernelGGL(cvtTx_k, dim3(DIN/64, NN/64), dim3(256), 0, stream, x, xT_bf);
  hipLaunchKernelGGL(cvtT4_k, dim3(8, 24, 4), dim3(256), 0, stream,
                     ego_W, egoWT, cut_W, cutWT, glob_W, globWT, fc_W, fcWT);

  // ---- features ----
  hipLaunchKernelGGL(bitgemm_k, dim3(NN/64, DIN/64, 4), dim3(256), 0, stream, reach, xT_bf, pbuf);
  hipLaunchKernelGGL(redscale_k, dim3((NN*DIN/4)/256), dim3(256), 0, stream, pbuf, cntinv, ego_bf);
  hipLaunchKernelGGL(cut_k, dim3(NN), dim3(256), 0, stream, x, out_off, outdeg, out_list, cut_bf);
  hipLaunchKernelGGL(aggfeat_k, dim3(NN), dim3(256), 0, stream,
                     ego_bf, cut_bf, in_off, indeg, in_list, aggE_bf, aggC_bf);

  // ---- encoders (fused indeg*bias + relu -> bf16 concat) ----
  hipLaunchKernelGGL(gemm3_k, dim3(DHID/64, NN/64, 3), dim3(256), 0, stream,
                     aggE_bf, aggC_bf, x_bf, egoWT, cutWT, globWT,
                     ego_b, cut_b, glob_b, indeg, hcat);

  // ---- fc + log_softmax ----
  hipLaunchKernelGGL(fcgemm_k, dim3(NN/64, 4), dim3(256), 0, stream, hcat, fcWT, fcpart);
  hipLaunchKernelGGL(fcfin_k, dim3(NN), dim3(64), 0, stream, fcpart, fc_b, out);
}

// Round 8
// 193.003 us; speedup vs baseline: 3.8644x; 1.2130x over previous
//
#include <hip/hip_runtime.h>

#define NN 4096
#define NE 131072
#define DIN 256
#define DHID 512
#define DOUT 64
#define DCAT 1536
#define NBINS 65536
#define HALF_E 65536

typedef __attribute__((ext_vector_type(8))) short short8;
typedef __attribute__((ext_vector_type(4))) float f32x4;

__device__ inline unsigned short bf16rne(float f){
  unsigned u = __float_as_uint(f);
  unsigned r = u + 0x7FFFu + ((u>>16)&1u);
  return (unsigned short)(r>>16);
}
__device__ inline float bf2f(unsigned short u){ return __uint_as_float(((unsigned)u)<<16); }

// ---------------- Threefry-2x32 (JAX-compatible) ----------------
struct K2 { unsigned a, b; };
__host__ __device__ constexpr unsigned rotl32(unsigned x, unsigned d){ return (x<<d)|(x>>(32u-d)); }
__host__ __device__ constexpr K2 tf2x32(unsigned k0, unsigned k1, unsigned x0, unsigned x1){
  unsigned k2 = k0 ^ k1 ^ 0x1BD11BDAu;
  x0 += k0; x1 += k1;
  x0+=x1; x1=rotl32(x1,13); x1^=x0;
  x0+=x1; x1=rotl32(x1,15); x1^=x0;
  x0+=x1; x1=rotl32(x1,26); x1^=x0;
  x0+=x1; x1=rotl32(x1, 6); x1^=x0;
  x0+=k1; x1+=k2+1u;
  x0+=x1; x1=rotl32(x1,17); x1^=x0;
  x0+=x1; x1=rotl32(x1,29); x1^=x0;
  x0+=x1; x1=rotl32(x1,16); x1^=x0;
  x0+=x1; x1=rotl32(x1,24); x1^=x0;
  x0+=k2; x1+=k0+2u;
  x0+=x1; x1=rotl32(x1,13); x1^=x0;
  x0+=x1; x1=rotl32(x1,15); x1^=x0;
  x0+=x1; x1=rotl32(x1,26); x1^=x0;
  x0+=x1; x1=rotl32(x1, 6); x1^=x0;
  x0+=k0; x1+=k1+3u;
  x0+=x1; x1=rotl32(x1,17); x1^=x0;
  x0+=x1; x1=rotl32(x1,29); x1^=x0;
  x0+=x1; x1=rotl32(x1,16); x1^=x0;
  x0+=x1; x1=rotl32(x1,24); x1^=x0;
  x0+=k1; x1+=k2+4u;
  x0+=x1; x1=rotl32(x1,13); x1^=x0;
  x0+=x1; x1=rotl32(x1,15); x1^=x0;
  x0+=x1; x1=rotl32(x1,26); x1^=x0;
  x0+=x1; x1=rotl32(x1, 6); x1^=x0;
  x0+=k2; x1+=k0+5u;
  return K2{x0,x1};
}
static_assert(tf2x32(0u,0u,0u,2u).a==4146024105u, "threefry mismatch o0");
static_assert(tf2x32(0u,0u,0u,2u).b==2718843009u, "threefry mismatch o1");
static_assert(tf2x32(0u,0u,1u,3u).a==967050713u,  "threefry mismatch o0b");
static_assert(tf2x32(0u,0u,1u,3u).b==1272950319u, "threefry mismatch o1b");

// partitionable threefry (verified passing r4-r7)
constexpr K2 E0 = tf2x32(0u,42u,0u,0u);     // key1
constexpr K2 E1 = tf2x32(0u,42u,0u,1u);     // sub1
constexpr unsigned SK1A = E1.a, SK1B = E1.b;
constexpr K2 F1 = tf2x32(E0.a,E0.b,0u,1u);  // sub2
constexpr unsigned SK2A = F1.a, SK2B = F1.b;

// med buffer layout (unsigned): [0]=hstar [1]=base [2]=cnt [3]=lo_cut [4]=rk_cut
// [8..71]=lo list, [72..135]=rk list  (capacity 64)
#define MED_CAP 64

// keys + histograms + degrees + one-hop bits, all per-edge fused
__global__ void genkeysdeg_k(const int* __restrict__ ei,
                             unsigned* __restrict__ keys1, unsigned* __restrict__ keys2,
                             unsigned* __restrict__ hist1, unsigned* __restrict__ hist2,
                             unsigned* __restrict__ indeg, unsigned* __restrict__ outdeg,
                             unsigned* __restrict__ bits){
  unsigned e = blockIdx.x*256u + threadIdx.x;
  K2 r1 = tf2x32(SK1A, SK1B, 0u, e);
  unsigned k1 = r1.a ^ r1.b;
  K2 r2 = tf2x32(SK2A, SK2B, 0u, e);
  unsigned k2 = r2.a ^ r2.b;
  keys1[e] = k1; keys2[e] = k2;
  atomicAdd(&hist1[k1>>16], 1u);
  atomicAdd(&hist2[k2>>16], 1u);
  unsigned s = (unsigned)ei[e], d = (unsigned)ei[NE+e];
  atomicAdd(&outdeg[s], 1u);
  atomicAdd(&indeg[d], 1u);
  atomicOr(&bits[d*128 + (s>>5)], 1u << (s&31));
  if (e < NN) atomicOr(&bits[e*128 + (e>>5)], 1u << (e&31));
}

// ---------------- 3-phase quad exclusive scan (y: 0=hist1,1=hist2,2=indeg,3=outdeg) ----------------
__global__ void scanA_k(const unsigned* __restrict__ in0, const unsigned* __restrict__ in1,
                        const unsigned* __restrict__ in2, const unsigned* __restrict__ in3,
                        unsigned* __restrict__ o0, unsigned* __restrict__ o1,
                        unsigned* __restrict__ o2, unsigned* __restrict__ o3,
                        unsigned* __restrict__ bsum){
  int y = blockIdx.y;
  int n = (y<2) ? NBINS : NN;
  if ((int)blockIdx.x*256 >= n) return;
  const unsigned* in = y==0?in0 : y==1?in1 : y==2?in2 : in3;
  unsigned* o        = y==0?o0  : y==1?o1  : y==2?o2  : o3;
  __shared__ unsigned s[256];
  int t = threadIdx.x; unsigned i = blockIdx.x*256u + t;
  unsigned v = in[i]; s[t] = v; __syncthreads();
  for (int off=1; off<256; off<<=1){
    unsigned u = (t>=off)?s[t-off]:0u; __syncthreads();
    s[t]+=u; __syncthreads();
  }
  o[i] = s[t]-v;
  if (t==255) bsum[y*256 + blockIdx.x] = s[255];
}
__global__ void scanB_k(unsigned* __restrict__ bsum){
  __shared__ unsigned s[256];
  int y = blockIdx.x, t = threadIdx.x;
  int nb = (y<2) ? 256 : 16;
  unsigned* b = bsum + y*256;
  unsigned v = (t<nb)?b[t]:0u; s[t]=v; __syncthreads();
  for (int off=1; off<256; off<<=1){
    unsigned u=(t>=off)?s[t-off]:0u; __syncthreads();
    s[t]+=u; __syncthreads();
  }
  if (t<nb) b[t]=s[t]-v;
}
__global__ void scanC_k(unsigned* __restrict__ o0, unsigned* __restrict__ o1,
                        unsigned* __restrict__ o2, unsigned* __restrict__ o3,
                        unsigned* __restrict__ c0, unsigned* __restrict__ c1,
                        unsigned* __restrict__ c2, unsigned* __restrict__ c3,
                        const unsigned* __restrict__ bsum){
  int y = blockIdx.y;
  int n = (y<2) ? NBINS : NN;
  if ((int)blockIdx.x*256 >= n) return;
  unsigned* o = y==0?o0 : y==1?o1 : y==2?o2 : o3;
  unsigned* c = y==0?c0 : y==1?c1 : y==2?c2 : c3;
  unsigned i = blockIdx.x*256u + threadIdx.x;
  unsigned v = o[i] + bsum[y*256 + blockIdx.x];
  o[i]=v; c[i]=v;
}

// locate bin containing global position HALF_E
__global__ void med1_k(const unsigned* __restrict__ prefix2, const unsigned* __restrict__ hist2,
                       unsigned* __restrict__ med){
  unsigned h = blockIdx.x*256u + threadIdx.x;
  unsigned p = prefix2[h], n = hist2[h];
  if (p <= HALF_E && HALF_E < p + n){ med[0] = h; med[1] = p; }
}

// ---------------- rank passes ----------------
__global__ void scat1_k(const unsigned* __restrict__ keys1, unsigned* __restrict__ cursor,
                        unsigned* __restrict__ slow, unsigned* __restrict__ stb){
  int e = blockIdx.x*256 + threadIdx.x;
  unsigned k = keys1[e];
  unsigned p = atomicAdd(&cursor[k>>16], 1u);
  slow[p] = k & 0xFFFFu; stb[p] = (unsigned)e;
}
// rank1 + append members of bin h* (their round-2 sort identity (lo16, rk))
__global__ void rank1_k(const unsigned* __restrict__ keys1, const unsigned* __restrict__ prefix,
                        const unsigned* __restrict__ hist, const unsigned* __restrict__ slow,
                        const unsigned* __restrict__ stb, const unsigned* __restrict__ keys2,
                        unsigned* __restrict__ rank1, unsigned* __restrict__ med){
  int e = blockIdx.x*256 + threadIdx.x;
  unsigned k = keys1[e], h = k>>16, lo = k & 0xFFFFu, tb = (unsigned)e;
  unsigned base = prefix[h], n = hist[h], r = 0;
  for (unsigned j=0;j<n;j++){
    unsigned l2 = slow[base+j], t2 = stb[base+j];
    if (l2 < lo || (l2==lo && t2 < tb)) r++;
  }
  unsigned rk = base + r;
  rank1[e] = rk;
  unsigned k2 = keys2[rk];
  if ((k2>>16) == med[0]){
    unsigned idx = atomicAdd(&med[2], 1u);
    if (idx < MED_CAP){ med[8+idx] = k2 & 0xFFFFu; med[72+idx] = rk; }
  }
}
// rank bin-h* members; emit the cut element (in-bin index HALF_E - base)
__global__ void med3_k(unsigned* __restrict__ med){
  int t = threadIdx.x;
  unsigned n = med[2]; if (n > MED_CAP) n = MED_CAP;
  unsigned qcut = HALF_E - med[1];
  if (t < (int)n){
    unsigned lo = med[8+t], rk = med[72+t], pos = 0;
    for (unsigned j=0;j<n;j++){
      unsigned lj = med[8+j], rj = med[72+j];
      if (lj < lo || (lj==lo && rj < rk)) pos++;
    }
    if (pos == qcut){ med[3] = lo; med[4] = rk; }
  }
}

// ---------------- CSR scatter + inline keep ----------------
__global__ void scatter_edges_k(const int* __restrict__ ei, const unsigned* __restrict__ rank1,
                                const unsigned* __restrict__ keys2, const unsigned* __restrict__ med,
                                unsigned* __restrict__ curin, unsigned* __restrict__ curout,
                                unsigned* __restrict__ in_list, unsigned* __restrict__ out_list){
  int e = blockIdx.x*256 + threadIdx.x;
  unsigned s = (unsigned)ei[e], d = (unsigned)ei[NE+e];
  unsigned rk = rank1[e], k2 = keys2[rk];
  unsigned h = k2>>16, lo = k2 & 0xFFFFu;
  unsigned hs = med[0], loc = med[3], rkc = med[4];
  unsigned keep = (h > hs) || (h == hs && (lo > loc || (lo == loc && rk >= rkc)));
  unsigned p = atomicAdd(&curin[d], 1u);  in_list[p] = s;
  unsigned q = atomicAdd(&curout[s], 1u); out_list[q] = d | (keep<<31);
}

// ---------------- 2-hop reach + popcount ----------------
__global__ void reach_k(const unsigned* __restrict__ bits, const unsigned* __restrict__ in_off,
                        const unsigned* __restrict__ in_list, const unsigned* __restrict__ indeg,
                        unsigned* __restrict__ reach, float* __restrict__ cntinv){
  __shared__ int ws2[2];
  int i = blockIdx.x, t = threadIdx.x;   // 128 threads
  unsigned off = in_off[i], deg = indeg[i];
  unsigned acc = bits[i*128 + t];
  for (unsigned j=0;j<deg;j++) acc |= bits[in_list[off+j]*128 + t];
  reach[i*128 + t] = acc;
  int c = __popc(acc);
  for (int o=32;o>0;o>>=1) c += __shfl_xor(c, o, 64);
  if ((t&63)==0) ws2[t>>6] = c;
  __syncthreads();
  if (t==0) cntinv[i] = 1.0f / (float)(ws2[0]+ws2[1]);
}

// ---------------- all conversions in one flat-grid kernel ----------------
__device__ inline void tconv(const float* __restrict__ src, unsigned short* __restrict__ dst,
                             int R, int C, int r0, int c0){
  __shared__ unsigned short tile[64][72];
  int t = threadIdx.x;
  int tr = t>>2, tc = (t&3)*16;
  #pragma unroll
  for (int u=0;u<16;u++)
    tile[tr][tc+u] = bf16rne(src[(size_t)(r0+tr)*C + c0 + tc + u]);
  __syncthreads();
  unsigned short v[16];
  #pragma unroll
  for (int u=0;u<16;u++) v[u] = tile[tc+u][tr];
  uint4* vv = (uint4*)v;
  uint4* o = (uint4*)&dst[(size_t)(c0+tr)*R + r0 + tc];
  o[0] = vv[0]; o[1] = vv[1];
}
__global__ void convall_k(const float* __restrict__ x, unsigned short* __restrict__ x_bf,
                          unsigned short* __restrict__ xT_bf,
                          const float* __restrict__ W0, unsigned short* __restrict__ WT0,
                          const float* __restrict__ W1, unsigned short* __restrict__ WT1,
                          const float* __restrict__ W2, unsigned short* __restrict__ WT2,
                          const float* __restrict__ fcW, unsigned short* __restrict__ fcWT){
  int b = blockIdx.x, t = threadIdx.x;
  if (b < 1024){                                        // x -> x_bf (flat, 4/thread)
    int i = b*256 + t;
    float4 f = ((const float4*)x)[i];
    uint2 o;
    o.x = (unsigned)bf16rne(f.x) | ((unsigned)bf16rne(f.y)<<16);
    o.y = (unsigned)bf16rne(f.z) | ((unsigned)bf16rne(f.w)<<16);
    ((uint2*)x_bf)[i] = o;
  } else if (b < 1280){                                 // x^T: R=4096, C=256, tiles 4x64
    int idx = b - 1024;
    tconv(x, xT_bf, NN, DIN, (idx>>2)*64, (idx&3)*64);
  } else if (b < 1376){                                 // 3 enc weights: R=256, C=512, 32 tiles each
    int idx = b - 1280;
    int z = idx >> 5, tl = idx & 31;
    const float* src = z==0?W0 : z==1?W1 : W2;
    unsigned short* dst = z==0?WT0 : z==1?WT1 : WT2;
    tconv(src, dst, DIN, DHID, (tl>>3)*64, (tl&7)*64);
  } else {                                              // fcW: R=1536, C=64, 24 tiles
    int by = b - 1376;
    tconv(fcW, fcWT, DCAT, DOUT, by*64, 0);
  }
}

// ---------------- ego bit-GEMM, split-K=4, K_STEP=128 ----------------
__global__ void bitgemm_k(const unsigned* __restrict__ reach, const unsigned short* __restrict__ xT,
                          float* __restrict__ pbuf){
  __shared__ __align__(16) unsigned short bt[4][64*32];
  int t = threadIdx.x, w = t>>6, l = t&63;
  int m0 = blockIdx.x*64, n0 = blockIdx.y*64;
  int kbase = blockIdx.z*(NN/4);
  int srow = t>>2, sg = t&3;
  int arow = m0 + 16*w + (l&15);
  int lg = l>>4;
  f32x4 acc[4];
  #pragma unroll
  for (int c=0;c<4;c++) acc[c] = f32x4{0.f,0.f,0.f,0.f};

  for (int it=0; it<8; ++it){
    int kk = kbase + it*128;
    __syncthreads();
    #pragma unroll
    for (int s=0;s<4;s++){
      uint4 v = *(const uint4*)&xT[(size_t)(n0+srow)*NN + kk + 32*s + sg*8];
      *(uint4*)&bt[s][srow*32 + ((sg ^ (srow&3))*8)] = v;
    }
    __syncthreads();
    unsigned rw[4];
    *(uint4*)rw = *(const uint4*)&reach[(size_t)arow*128 + (kk>>5)];
    #pragma unroll
    for (int s=0;s<4;s++){
      unsigned byte = (rw[s] >> (8*lg)) & 0xFFu;
      union { short8 s8; unsigned u[4]; } af;
      #pragma unroll
      for (int pp=0;pp<4;pp++){
        unsigned b0 = (byte>>(2*pp))&1u, b1 = (byte>>(2*pp+1))&1u;
        af.u[pp] = b0*0x3F80u | b1*0x3F800000u;
      }
      #pragma unroll
      for (int c=0;c<4;c++){
        int brow = 16*c + (l&15);
        short8 bf = *(const short8*)&bt[s][brow*32 + ((lg ^ (brow&3))*8)];
        acc[c] = __builtin_amdgcn_mfma_f32_16x16x32_bf16(af.s8, bf, acc[c], 0,0,0);
      }
    }
  }
  size_t zoff = (size_t)blockIdx.z*NN*DIN;
  #pragma unroll
  for (int c=0;c<4;c++){
    #pragma unroll
    for (int r=0;r<4;r++){
      int row = m0 + 16*w + 4*lg + r;
      int col = n0 + 16*c + (l&15);
      pbuf[zoff + (size_t)row*DIN + col] = acc[c][r];
    }
  }
}

// ---------------- fused: redscale (blocks 0..1023) + cut feature (blocks 1024..5119) ----------------
__global__ void redcut_k(const float* __restrict__ pbuf, const float* __restrict__ cntinv,
                         unsigned short* __restrict__ ego_bf,
                         const float* __restrict__ x, const unsigned* __restrict__ out_off,
                         const unsigned* __restrict__ outdeg, const unsigned* __restrict__ out_list,
                         unsigned short* __restrict__ cut_bf){
  int b = blockIdx.x, t = threadIdx.x;
  if (b < 1024){
    int g = b*256 + t;
    const size_t S = (size_t)NN*DIN/4;
    const float4* p4 = (const float4*)pbuf;
    float4 a = p4[g], bb = p4[g+S], c = p4[g+2*S], d = p4[g+3*S];
    int row = (g*4)>>8;
    float ci = cntinv[row];
    float vx = (a.x+bb.x+c.x+d.x)*ci, vy = (a.y+bb.y+c.y+d.y)*ci;
    float vz = (a.z+bb.z+c.z+d.z)*ci, vw = (a.w+bb.w+c.w+d.w)*ci;
    uint2 o;
    o.x = (unsigned)bf16rne(vx) | ((unsigned)bf16rne(vy)<<16);
    o.y = (unsigned)bf16rne(vz) | ((unsigned)bf16rne(vw)<<16);
    ((uint2*)ego_bf)[g] = o;
  } else {
    int s = b - 1024;
    unsigned off = out_off[s], deg = outdeg[s];
    float acc = 0.f; int cnt = 0;
    for (unsigned j=0;j<deg;j++){
      unsigned p = out_list[off+j];
      if (p >> 31){ cnt++; acc += x[(p & 0xFFFFu)*DIN + t]; }
    }
    float v = cnt ? acc / (float)cnt : x[s*DIN + t];
    cut_bf[(size_t)s*DIN + t] = bf16rne(v);
  }
}

// ---------------- aggregate 256-dim features over in-edges (linearity trick) ----------------
__global__ void aggfeat_k(const unsigned short* __restrict__ ego_bf, const unsigned short* __restrict__ cut_bf,
                          const unsigned* __restrict__ in_off, const unsigned* __restrict__ indeg,
                          const unsigned* __restrict__ in_list,
                          unsigned short* __restrict__ aggE, unsigned short* __restrict__ aggC){
  int i = blockIdx.x, t = threadIdx.x;
  unsigned off = in_off[i], deg = indeg[i];
  float ae = 0.f, ac = 0.f;
  for (unsigned j=0;j<deg;j++){
    unsigned s = in_list[off+j];
    ae += bf2f(ego_bf[(size_t)s*DIN + t]);
    ac += bf2f(cut_bf[(size_t)s*DIN + t]);
  }
  aggE[(size_t)i*DIN + t] = bf16rne(ae);
  aggC[(size_t)i*DIN + t] = bf16rne(ac);
}

// ---------------- merged encoder GEMM (z: 0=ego-agg,1=cut-agg,2=glob) ----------------
__global__ void gemm3_k(const unsigned short* __restrict__ aggE, const unsigned short* __restrict__ aggC,
                        const unsigned short* __restrict__ xbf,
                        const unsigned short* __restrict__ WTe, const unsigned short* __restrict__ WTc,
                        const unsigned short* __restrict__ WTg,
                        const float* __restrict__ eb, const float* __restrict__ cb, const float* __restrict__ gb,
                        const unsigned* __restrict__ indeg, unsigned short* __restrict__ hcat){
  __shared__ __align__(16) unsigned short at[4][64*32];
  __shared__ __align__(16) unsigned short bt[4][64*32];
  int z = blockIdx.z;
  const unsigned short* A  = z==0? aggE : z==1? aggC : xbf;
  const unsigned short* BT = z==0? WTe  : z==1? WTc  : WTg;
  const float* bias        = z==0? eb   : z==1? cb   : gb;
  int t = threadIdx.x, w = t>>6, l = t&63;
  int n0 = blockIdx.x*64, m0 = blockIdx.y*64;
  int srow = t>>2, sg = t&3;
  int lg = l>>4;
  f32x4 acc[4];
  #pragma unroll
  for (int c=0;c<4;c++) acc[c] = f32x4{0.f,0.f,0.f,0.f};

  for (int it=0; it<2; ++it){
    int kk = it*128;
    __syncthreads();
    #pragma unroll
    for (int s=0;s<4;s++){
      uint4 va = *(const uint4*)&A [(size_t)(m0+srow)*DIN + kk + 32*s + sg*8];
      uint4 vb = *(const uint4*)&BT[(size_t)(n0+srow)*DIN + kk + 32*s + sg*8];
      *(uint4*)&at[s][srow*32 + ((sg ^ (srow&3))*8)] = va;
      *(uint4*)&bt[s][srow*32 + ((sg ^ (srow&3))*8)] = vb;
    }
    __syncthreads();
    int ar = 16*w + (l&15);
    #pragma unroll
    for (int s=0;s<4;s++){
      short8 af = *(const short8*)&at[s][ar*32 + ((lg ^ (ar&3))*8)];
      #pragma unroll
      for (int c=0;c<4;c++){
        int brow = 16*c + (l&15);
        short8 bf = *(const short8*)&bt[s][brow*32 + ((lg ^ (brow&3))*8)];
        acc[c] = __builtin_amdgcn_mfma_f32_16x16x32_bf16(af, bf, acc[c], 0,0,0);
      }
    }
  }
  #pragma unroll
  for (int c=0;c<4;c++){
    #pragma unroll
    for (int r=0;r<4;r++){
      int row = m0 + 16*w + 4*lg + r;
      int col = n0 + 16*c + (l&15);
      float scale = (z<2) ? (float)indeg[row] : 1.0f;
      float v = acc[c][r] + bias[col]*scale;
      if (z<2) v = fmaxf(v, 0.f);
      hcat[(size_t)row*DCAT + z*DHID + col] = bf16rne(v);
    }
  }
}

// ---------------- fc GEMM split-K=4 ----------------
__global__ void fcgemm_k(const unsigned short* __restrict__ hcat, const unsigned short* __restrict__ fcWT,
                         float* __restrict__ fcpart){
  __shared__ __align__(16) unsigned short at[4][64*32];
  __shared__ __align__(16) unsigned short bt[4][64*32];
  int t = threadIdx.x, w = t>>6, l = t&63;
  int m0 = blockIdx.x*64;
  int kbase = blockIdx.y*(DCAT/4);
  int srow = t>>2, sg = t&3;
  int lg = l>>4;
  f32x4 acc[4];
  #pragma unroll
  for (int c=0;c<4;c++) acc[c] = f32x4{0.f,0.f,0.f,0.f};

  for (int it=0; it<3; ++it){
    int kk = kbase + it*128;
    __syncthreads();
    #pragma unroll
    for (int s=0;s<4;s++){
      uint4 va = *(const uint4*)&hcat [(size_t)(m0+srow)*DCAT + kk + 32*s + sg*8];
      uint4 vb = *(const uint4*)&fcWT[(size_t)srow*DCAT + kk + 32*s + sg*8];
      *(uint4*)&at[s][srow*32 + ((sg ^ (srow&3))*8)] = va;
      *(uint4*)&bt[s][srow*32 + ((sg ^ (srow&3))*8)] = vb;
    }
    __syncthreads();
    int ar = 16*w + (l&15);
    #pragma unroll
    for (int s=0;s<4;s++){
      short8 af = *(const short8*)&at[s][ar*32 + ((lg ^ (ar&3))*8)];
      #pragma unroll
      for (int c=0;c<4;c++){
        int brow = 16*c + (l&15);
        short8 bf = *(const short8*)&bt[s][brow*32 + ((lg ^ (brow&3))*8)];
        acc[c] = __builtin_amdgcn_mfma_f32_16x16x32_bf16(af, bf, acc[c], 0,0,0);
      }
    }
  }
  size_t zoff = (size_t)blockIdx.y*NN*DOUT;
  #pragma unroll
  for (int c=0;c<4;c++){
    #pragma unroll
    for (int r=0;r<4;r++){
      int row = m0 + 16*w + 4*lg + r;
      int col = 16*c + (l&15);
      fcpart[zoff + (size_t)row*DOUT + col] = acc[c][r];
    }
  }
}

// ---------------- finish: sum partials + bias + log_softmax ----------------
__global__ void fcfin_k(const float* __restrict__ fcpart, const float* __restrict__ fcb,
                        float* __restrict__ out){
  int i = blockIdx.x, l = threadIdx.x;
  const size_t S = (size_t)NN*DOUT;
  size_t idx = (size_t)i*DOUT + l;
  float v = fcpart[idx] + fcpart[idx+S] + fcpart[idx+2*S] + fcpart[idx+3*S] + fcb[l];
  float m = v;
  for (int o=32;o>0;o>>=1) m = fmaxf(m, __shfl_xor(m, o, 64));
  float e = __expf(v - m), s = e;
  for (int o=32;o>0;o>>=1) s += __shfl_xor(s, o, 64);
  out[idx] = (v - m) - logf(s);
}

// ---------------- host launch ----------------
static inline size_t alignup(size_t x){ return (x + 255) & ~(size_t)255; }

extern "C" void kernel_launch(void* const* d_in, const int* in_sizes, int n_in,
                              void* d_out, int out_size, void* d_ws, size_t ws_size,
                              hipStream_t stream) {
  const float* x      = (const float*)d_in[0];
  const int*   ei     = (const int*)  d_in[1];
  const float* ego_W  = (const float*)d_in[2];
  const float* ego_b  = (const float*)d_in[3];
  const float* cut_W  = (const float*)d_in[4];
  const float* cut_b  = (const float*)d_in[5];
  const float* glob_W = (const float*)d_in[6];
  const float* glob_b = (const float*)d_in[7];
  const float* fc_W   = (const float*)d_in[8];
  const float* fc_b   = (const float*)d_in[9];
  float* out = (float*)d_out;

  char* base = (char*)d_ws;
  char* p = base;
  #define ALLOC(ty, name, cnt) ty* name = (ty*)p; p += alignup(sizeof(ty)*(size_t)(cnt));
  ALLOC(char,           R0,      (size_t)4*NN*DIN*4);   // 16MB: sort temps -> pbuf -> hcat
  // ---- zero region (one memset: bits..med) ----
  ALLOC(unsigned,       bits,    NN*128);
  ALLOC(unsigned,       indeg,   NN);
  ALLOC(unsigned,       outdeg,  NN);
  ALLOC(unsigned,       hist1,   NBINS);
  ALLOC(unsigned,       hist2,   NBINS);
  ALLOC(unsigned,       med,     256);
  char* zero_end = p;
  // ---- rest ----
  ALLOC(unsigned,       in_off,  NN);
  ALLOC(unsigned,       out_off, NN);
  ALLOC(unsigned,       curin,   NN);
  ALLOC(unsigned,       curout,  NN);
  ALLOC(unsigned,       in_list, NE);
  ALLOC(unsigned,       out_list,NE);
  ALLOC(unsigned,       reach,   NN*128);
  ALLOC(float,          cntinv,  NN);
  ALLOC(unsigned short, x_bf,    (size_t)NN*DIN);
  ALLOC(unsigned short, xT_bf,   (size_t)DIN*NN);
  ALLOC(unsigned short, ego_bf,  (size_t)NN*DIN);
  ALLOC(unsigned short, cut_bf,  (size_t)NN*DIN);
  ALLOC(unsigned short, aggE_bf, (size_t)NN*DIN);
  ALLOC(unsigned short, aggC_bf, (size_t)NN*DIN);
  ALLOC(unsigned short, egoWT,   (size_t)DHID*DIN);
  ALLOC(unsigned short, cutWT,   (size_t)DHID*DIN);
  ALLOC(unsigned short, globWT,  (size_t)DHID*DIN);
  ALLOC(unsigned short, fcWT,    (size_t)DOUT*DCAT);
  ALLOC(unsigned,       prefix1, NBINS);
  ALLOC(unsigned,       cursor1, NBINS);
  ALLOC(unsigned,       prefix2, NBINS);
  ALLOC(unsigned,       cursor2, NBINS);
  ALLOC(unsigned,       bsum,    1024);
  ALLOC(float,          fcpart,  (size_t)4*NN*DOUT);
  #undef ALLOC
  size_t need = (size_t)(p - base);
  if (ws_size < need){
    hipMemsetAsync(d_out, 0x7F, (size_t)out_size*sizeof(float), stream);
    return;
  }
  float*          pbuf = (float*)R0;
  unsigned short* hcat = (unsigned short*)R0;
  char* q = R0;
  #define OALLOC(ty, name, cnt) ty* name = (ty*)q; q += alignup(sizeof(ty)*(size_t)(cnt));
  OALLOC(unsigned, keys1,  NE);
  OALLOC(unsigned, keys2,  NE);
  OALLOC(unsigned, rank1,  NE);
  OALLOC(unsigned, slow,   NE);
  OALLOC(unsigned, stb,    NE);
  #undef OALLOC

  const int EB = NE/256;

  // 1) single memset over [bits|indeg|outdeg|hist1|hist2|med]
  hipMemsetAsync(bits, 0, (size_t)(zero_end - (char*)bits), stream);
  // 2) keys + hists + degrees + one-hop bits
  hipLaunchKernelGGL(genkeysdeg_k, dim3(EB), dim3(256), 0, stream,
                     ei, keys1, keys2, hist1, hist2, indeg, outdeg, bits);
  // 3-5) quad scan: hist1->prefix1/cursor1, hist2->prefix2/cursor2, indeg->in_off/curin, outdeg->out_off/curout
  hipLaunchKernelGGL(scanA_k, dim3(NBINS/256, 4), dim3(256), 0, stream,
                     hist1, hist2, indeg, outdeg, prefix1, prefix2, in_off, out_off, bsum);
  hipLaunchKernelGGL(scanB_k, dim3(4), dim3(256), 0, stream, bsum);
  hipLaunchKernelGGL(scanC_k, dim3(NBINS/256, 4), dim3(256), 0, stream,
                     prefix1, prefix2, in_off, out_off, cursor1, cursor2, curin, curout, bsum);
  // 6) locate median bin of keys2
  hipLaunchKernelGGL(med1_k, dim3(NBINS/256), dim3(256), 0, stream, prefix2, hist2, med);
  // 7-9) round-1 rank (+ median-bin collection), cut-element selection
  hipLaunchKernelGGL(scat1_k, dim3(EB), dim3(256), 0, stream, keys1, cursor1, slow, stb);
  hipLaunchKernelGGL(rank1_k, dim3(EB), dim3(256), 0, stream,
                     keys1, prefix1, hist1, slow, stb, keys2, rank1, med);
  hipLaunchKernelGGL(med3_k, dim3(1), dim3(64), 0, stream, med);
  // 10) CSR scatter + inline keep
  hipLaunchKernelGGL(scatter_edges_k, dim3(EB), dim3(256), 0, stream,
                     ei, rank1, keys2, med, curin, curout, in_list, out_list);
  // 11) 2-hop reach
  hipLaunchKernelGGL(reach_k, dim3(NN), dim3(128), 0, stream,
                     bits, in_off, in_list, indeg, reach, cntinv);
  // 12) all conversions
  hipLaunchKernelGGL(convall_k, dim3(1400), dim3(256), 0, stream,
                     x, x_bf, xT_bf, ego_W, egoWT, cut_W, cutWT, glob_W, globWT, fc_W, fcWT);
  // 13) ego bit-GEMM (pbuf overlays sort temps; keys2/rank1 dead after step 10)
  hipLaunchKernelGGL(bitgemm_k, dim3(NN/64, DIN/64, 4), dim3(256), 0, stream, reach, xT_bf, pbuf);
  // 14) redscale + cut
  hipLaunchKernelGGL(redcut_k, dim3(5120), dim3(256), 0, stream,
                     pbuf, cntinv, ego_bf, x, out_off, outdeg, out_list, cut_bf);
  // 15) feature aggregation (linearity trick)
  hipLaunchKernelGGL(aggfeat_k, dim3(NN), dim3(256), 0, stream,
                     ego_bf, cut_bf, in_off, indeg, in_list, aggE_bf, aggC_bf);
  // 16) encoders -> hcat (overlays pbuf, dead after 14)
  hipLaunchKernelGGL(gemm3_k, dim3(DHID/64, NN/64, 3), dim3(256), 0, stream,
                     aggE_bf, aggC_bf, x_bf, egoWT, cutWT, globWT,
                     ego_b, cut_b, glob_b, indeg, hcat);
  // 17-18) fc + log_softmax
  hipLaunchKernelGGL(fcgemm_k, dim3(NN/64, 4), dim3(256), 0, stream, hcat, fcWT, fcpart);
  hipLaunchKernelGGL(fcfin_k, dim3(NN), dim3(64), 0, stream, fcpart, fc_b, out);
}